// Round 9
// baseline (401.018 us; speedup 1.0000x reference)
//
#include <hip/hip_runtime.h>
#include <math.h>

#define T_TOK 8192
#define DIMX 1024
#define NE 8
#define HID 2048
#define NPAIR (T_TOK * 2)
#define P_PAD (NPAIR + NE * 128)
#define GATE_TPB 32

typedef __attribute__((ext_vector_type(8))) short s16x8;
typedef __attribute__((ext_vector_type(4))) float f32x4;

static __device__ __forceinline__ unsigned short f2bf(float f) {
    union { float f; unsigned u; } v; v.f = f;
    unsigned r = v.u + 0x7FFFu + ((v.u >> 16) & 1u);
    return (unsigned short)(r >> 16);
}
static __device__ __forceinline__ float bf2f(unsigned short u) {
    union { unsigned u; float f; } v; v.u = (unsigned)u << 16; return v.f;
}

// gelu tanh approximation: v * sigmoid(1.5957691 * v * (1 + 0.044715 v^2))
// max abs err vs exact erf-GELU ~3e-4, below bf16 storage rounding.
static __device__ __forceinline__ float gelu_fast(float v) {
    float u2 = -1.5957691216057308f * v * (1.f + 0.044715f * v * v);
    return v * __builtin_amdgcn_rcpf(1.f + __expf(u2));
}

// async global->LDS, 16 bytes per lane. LDS dest must be wave-uniform base + lane*16.
static __device__ __forceinline__ void gload16(const unsigned short* g, unsigned short* l) {
    __builtin_amdgcn_global_load_lds(
        (const __attribute__((address_space(1))) unsigned int*)g,
        (__attribute__((address_space(3))) unsigned int*)l, 16, 0, 0);
}

// ---------------- init: routing slots + counts ----------------
__global__ void init_routing_kernel(int* slot_token, float* slot_weight, int* counts) {
    int i = blockIdx.x * blockDim.x + threadIdx.x;
    if (i < P_PAD) { slot_token[i] = 0; slot_weight[i] = 0.f; }
    if (i < NE) counts[i] = 0;
}

__global__ void convx_kernel(const float* __restrict__ x, unsigned short* __restrict__ xb) {
    int i = blockIdx.x * blockDim.x + threadIdx.x;  // one float4 each
    float4 f = ((const float4*)x)[i];
    unsigned short r[4] = { f2bf(f.x), f2bf(f.y), f2bf(f.z), f2bf(f.w) };
    *(uint2*)&xb[(size_t)i * 4] = *(const uint2*)&r[0];
}

// src [E][R][C] fp32 -> dst [E][C][R] bf16, 64x64 tiles, vectorized both sides
__global__ __launch_bounds__(256) void conv_transpose_kernel(
    const float* __restrict__ src, unsigned short* __restrict__ dst, int R, int C) {
    __shared__ float tile[64][65];
    int e = blockIdx.z;
    int r0 = blockIdx.y * 64, c0 = blockIdx.x * 64;
    const float* s = src + (size_t)e * R * C;
    unsigned short* d = dst + (size_t)e * R * C;
    int tid = threadIdx.x;
    int lr = tid >> 4, lc4 = (tid & 15) * 4;  // 16 rows per pass x 16 float4
    #pragma unroll
    for (int it = 0; it < 4; it++) {
        float4 v = *(const float4*)&s[(size_t)(r0 + it * 16 + lr) * C + c0 + lc4];
        tile[it * 16 + lr][lc4 + 0] = v.x;
        tile[it * 16 + lr][lc4 + 1] = v.y;
        tile[it * 16 + lr][lc4 + 2] = v.z;
        tile[it * 16 + lr][lc4 + 3] = v.w;
    }
    __syncthreads();
    int cc = tid >> 3, rch = (tid & 7) * 8;  // 32 dst rows per pass x 8 chunks of 8
    #pragma unroll
    for (int it = 0; it < 2; it++) {
        int c = it * 32 + cc;
        unsigned short r[8];
        #pragma unroll
        for (int j = 0; j < 8; j++) r[j] = f2bf(tile[rch + j][c]);
        *(uint4*)&d[(size_t)(c0 + c) * R + r0 + rch] = *(const uint4*)&r[0];
    }
}

// ---------------- gating: block-aggregated atomics ----------------
__global__ __launch_bounds__(256) void gate_kernel(
    const float* __restrict__ x, const float* __restrict__ gw, const float* __restrict__ gb,
    float* __restrict__ logits_out, int* counts, int* __restrict__ pair_epos,
    float* __restrict__ pair_w) {
    __shared__ float sgw[NE * DIMX];
    __shared__ int lcount[NE], lbase[NE];
    __shared__ int s_e[GATE_TPB * 2];
    __shared__ int s_lp[GATE_TPB * 2];
    __shared__ float s_wv[GATE_TPB * 2];
    int tid = threadIdx.x;
    for (int i = tid; i < NE * DIMX / 4; i += 256)
        ((float4*)sgw)[i] = ((const float4*)gw)[i];
    if (tid < NE) lcount[tid] = 0;
    __syncthreads();

    int wave = tid >> 6, lane = tid & 63;
    int tbase = blockIdx.x * GATE_TPB;
    for (int r = 0; r < GATE_TPB / 4; ++r) {
        int ti = wave * (GATE_TPB / 4) + r;
        int t = tbase + ti;
        const float* xr = x + (size_t)t * DIMX;
        float acc[NE] = {};
        #pragma unroll
        for (int i = 0; i < DIMX / 256; i++) {
            float4 xv = *(const float4*)&xr[i * 256 + lane * 4];
            #pragma unroll
            for (int e = 0; e < NE; e++) {
                float4 wv = *(const float4*)&sgw[e * DIMX + i * 256 + lane * 4];
                acc[e] += xv.x * wv.x + xv.y * wv.y + xv.z * wv.z + xv.w * wv.w;
            }
        }
        #pragma unroll
        for (int e = 0; e < NE; e++) {
            #pragma unroll
            for (int off = 32; off; off >>= 1) acc[e] += __shfl_xor(acc[e], off);
        }
        if (lane == 0) {
            float* lo = logits_out + (size_t)t * NE;
            #pragma unroll
            for (int e = 0; e < NE; e++) { acc[e] += gb[e]; lo[e] = acc[e]; }
            // top-2 (strict > keeps lowest index on ties, matching jax.lax.top_k)
            float l0 = acc[0]; int e0 = 0;
            #pragma unroll
            for (int e = 1; e < NE; e++) if (acc[e] > l0) { l0 = acc[e]; e0 = e; }
            float l1 = -1e30f; int e1 = -1;
            #pragma unroll
            for (int e = 0; e < NE; e++) if (e != e0 && acc[e] > l1) { l1 = acc[e]; e1 = e; }
            float q = expf(l1 - l0);
            float wn0 = 1.f / (1.f + q);
            float wn1 = q / (1.f + q);
            int lp0 = atomicAdd(&lcount[e0], 1);
            int lp1 = atomicAdd(&lcount[e1], 1);
            s_e[ti * 2] = e0; s_lp[ti * 2] = lp0; s_wv[ti * 2] = wn0;
            s_e[ti * 2 + 1] = e1; s_lp[ti * 2 + 1] = lp1; s_wv[ti * 2 + 1] = wn1;
        }
    }
    __syncthreads();
    if (tid < NE) lbase[tid] = atomicAdd(&counts[tid], lcount[tid]);
    __syncthreads();
    if (tid < GATE_TPB * 2) {
        int e = s_e[tid];
        int gp = lbase[e] + s_lp[tid];
        int gi = (tbase + (tid >> 1)) * 2 + (tid & 1);
        pair_epos[gi] = (e << 28) | gp;
        pair_w[gi] = s_wv[tid];
    }
}

__global__ void scan_kernel(const int* counts, int* offsets) {
    if (threadIdx.x == 0 && blockIdx.x == 0) {
        int o = 0;
        offsets[0] = 0;
        for (int e = 0; e < NE; e++) { o += (counts[e] + 127) & ~127; offsets[e + 1] = o; }
    }
}

__global__ void place_kernel(const int* __restrict__ pair_epos, const float* __restrict__ pair_w,
                             const int* __restrict__ offsets, int* __restrict__ slot_token,
                             float* __restrict__ slot_weight, int* __restrict__ tok2slot) {
    int p = blockIdx.x * 256 + threadIdx.x;
    if (p >= NPAIR) return;
    int ep = pair_epos[p];
    int e = ep >> 28;
    int pos = ep & 0x0FFFFFFF;
    int slot = offsets[e] + pos;
    slot_token[slot] = p >> 1;
    slot_weight[slot] = pair_w[p];
    tok2slot[p] = slot;
}

// shared pipeline pieces: 3-buffer LDS, stage depth 2, counted vmcnt, raw barriers.
#define BARRIER() asm volatile("s_barrier" ::: "memory")
#define WAIT_VM(n) asm volatile("s_waitcnt vmcnt(" #n ")" ::: "memory")
#define WAIT_LGKM0() do { asm volatile("s_waitcnt lgkmcnt(0)" ::: "memory"); \
                          __builtin_amdgcn_sched_barrier(0); } while (0)

// LDS layout (both tiles): K-major chunks, chunk c = kseg*128 + row, 16B each.
// Reader group (16 lanes, fixed kseg) sweeps 256 contiguous bytes -> conflict-free.

// ---------------- grouped GEMM 1: h = gelu(x @ W1 + b1) ----------------
// grid (8=expert, Nn, Nm): expert on blockIdx.x pins expert e -> XCD e (flat%8).
__global__ __launch_bounds__(256) void gemm1_kernel(
    const unsigned short* __restrict__ xb, const unsigned short* __restrict__ W1t,
    const float* __restrict__ b1, const int* __restrict__ offsets,
    const int* __restrict__ slot_token, unsigned short* __restrict__ hbuf) {
    int e = blockIdx.x;
    int row_base = offsets[e];
    int rows = offsets[e + 1] - row_base;
    int m0 = blockIdx.z * 128;
    if (m0 >= rows) return;
    int n0 = blockIdx.y * 128;

    __shared__ unsigned short sA[3][128 * 32];
    __shared__ unsigned short sB[3][128 * 32];

    int tid = threadIdx.x;
    const unsigned short* w1e = W1t + (size_t)e * HID * DIMX;

    // staging: thread tid owns chunks tid (kseg=tid>>7) and tid+256 (kseg+2), same row.
    int srow = tid & 127, sseg = tid >> 7;
    int tok = slot_token[row_base + m0 + srow];
    const unsigned short* gA0 = xb + (size_t)tok * DIMX + sseg * 8;
    const unsigned short* gB0 = w1e + (size_t)(n0 + srow) * DIMX + sseg * 8;

#define STG1(b, k0) do { \
        gload16(gA0 + (k0), &sA[b][tid * 8]); \
        gload16(gA0 + (k0) + 16, &sA[b][(tid + 256) * 8]); \
        gload16(gB0 + (k0), &sB[b][tid * 8]); \
        gload16(gB0 + (k0) + 16, &sB[b][(tid + 256) * 8]); \
    } while (0)

    f32x4 acc[4][4] = {};
    int wv = tid >> 6; int wr = wv >> 1, wc = wv & 1;
    int lane = tid & 63; int lr = lane & 15, lg = lane >> 4;

#define CMP1(CUR) do { \
        s16x8 af[4], bfr[4]; \
        _Pragma("unroll") \
        for (int m = 0; m < 4; m++) af[m] = *(const s16x8*)&sA[CUR][lg * 1024 + (wr * 64 + m * 16 + lr) * 8]; \
        _Pragma("unroll") \
        for (int n = 0; n < 4; n++) bfr[n] = *(const s16x8*)&sB[CUR][lg * 1024 + (wc * 64 + n * 16 + lr) * 8]; \
        __builtin_amdgcn_s_setprio(1); \
        _Pragma("unroll") \
        for (int m = 0; m < 4; m++) { \
            _Pragma("unroll") \
            for (int n = 0; n < 4; n++) \
                acc[m][n] = __builtin_amdgcn_mfma_f32_16x16x32_bf16(af[m], bfr[n], acc[m][n], 0, 0, 0); \
        } \
        __builtin_amdgcn_s_setprio(0); \
    } while (0)

    const int NT = DIMX / 32;
    STG1(0, 0);
    STG1(1, 32);
    int cur = 0;
    for (int t = 0; t < NT - 2; ++t) {
        int nxt = cur + 2; if (nxt >= 3) nxt -= 3;
        STG1(nxt, (t + 2) * 32);
        WAIT_VM(8);
        BARRIER();
        CMP1(cur);
        WAIT_LGKM0();
        BARRIER();
        cur = (cur + 1 == 3) ? 0 : cur + 1;
    }
    WAIT_VM(4);
    BARRIER();
    CMP1(cur);
    WAIT_LGKM0();
    BARRIER();
    cur = (cur + 1 == 3) ? 0 : cur + 1;
    WAIT_VM(0);
    BARRIER();
    CMP1(cur);
#undef STG1
#undef CMP1

    #pragma unroll
    for (int m = 0; m < 4; m++) {
        #pragma unroll
        for (int n = 0; n < 4; n++) {
            int col = n0 + wc * 64 + n * 16 + lr;
            float bias = b1[e * HID + col];
            #pragma unroll
            for (int i = 0; i < 4; i++) {
                int row = wr * 64 + m * 16 + lg * 4 + i;
                float v = gelu_fast(acc[m][n][i] + bias);
                hbuf[(size_t)(row_base + m0 + row) * HID + col] = f2bf(v);
            }
        }
    }
}

// ---------------- grouped GEMM 2: ybuf[slot] = w * (h @ W2 + b2), plain stores ----------------
__global__ __launch_bounds__(256) void gemm2_kernel(
    const unsigned short* __restrict__ hbuf, const unsigned short* __restrict__ W2t,
    const float* __restrict__ b2, const int* __restrict__ offsets,
    const float* __restrict__ slot_weight, unsigned short* __restrict__ ybuf) {
    int e = blockIdx.x;
    int row_base = offsets[e];
    int rows = offsets[e + 1] - row_base;
    int m0 = blockIdx.z * 128;
    if (m0 >= rows) return;
    int n0 = blockIdx.y * 128;

    __shared__ unsigned short sA[3][128 * 32];
    __shared__ unsigned short sB[3][128 * 32];
    __shared__ float s_w[128];

    int tid = threadIdx.x;
    if (tid < 128) s_w[tid] = slot_weight[row_base + m0 + tid];

    const unsigned short* ha = hbuf + (size_t)(row_base + m0) * HID;
    const unsigned short* w2e = W2t + (size_t)e * DIMX * HID;

    int srow = tid & 127, sseg = tid >> 7;
    const unsigned short* gA0 = ha + (size_t)srow * HID + sseg * 8;
    const unsigned short* gB0 = w2e + (size_t)(n0 + srow) * HID + sseg * 8;

#define STG2(b, k0) do { \
        gload16(gA0 + (k0), &sA[b][tid * 8]); \
        gload16(gA0 + (k0) + 16, &sA[b][(tid + 256) * 8]); \
        gload16(gB0 + (k0), &sB[b][tid * 8]); \
        gload16(gB0 + (k0) + 16, &sB[b][(tid + 256) * 8]); \
    } while (0)

    f32x4 acc[4][4] = {};
    int wv = tid >> 6; int wr = wv >> 1, wc = wv & 1;
    int lane = tid & 63; int lr = lane & 15, lg = lane >> 4;

#define CMP2(CUR) do { \
        s16x8 af[4], bfr[4]; \
        _Pragma("unroll") \
        for (int m = 0; m < 4; m++) af[m] = *(const s16x8*)&sA[CUR][lg * 1024 + (wr * 64 + m * 16 + lr) * 8]; \
        _Pragma("unroll") \
        for (int n = 0; n < 4; n++) bfr[n] = *(const s16x8*)&sB[CUR][lg * 1024 + (wc * 64 + n * 16 + lr) * 8]; \
        __builtin_amdgcn_s_setprio(1); \
        _Pragma("unroll") \
        for (int m = 0; m < 4; m++) { \
            _Pragma("unroll") \
            for (int n = 0; n < 4; n++) \
                acc[m][n] = __builtin_amdgcn_mfma_f32_16x16x32_bf16(af[m], bfr[n], acc[m][n], 0, 0, 0); \
        } \
        __builtin_amdgcn_s_setprio(0); \
    } while (0)

    const int NT = HID / 32;
    STG2(0, 0);
    STG2(1, 32);
    int cur = 0;
    for (int t = 0; t < NT - 2; ++t) {
        int nxt = cur + 2; if (nxt >= 3) nxt -= 3;
        STG2(nxt, (t + 2) * 32);
        WAIT_VM(8);
        BARRIER();
        CMP2(cur);
        WAIT_LGKM0();
        BARRIER();
        cur = (cur + 1 == 3) ? 0 : cur + 1;
    }
    WAIT_VM(4);
    BARRIER();
    CMP2(cur);
    WAIT_LGKM0();
    BARRIER();
    cur = (cur + 1 == 3) ? 0 : cur + 1;
    WAIT_VM(0);
    BARRIER();
    CMP2(cur);
#undef STG2
#undef CMP2

    #pragma unroll
    for (int m = 0; m < 4; m++) {
        #pragma unroll
        for (int n = 0; n < 4; n++) {
            int col = n0 + wc * 64 + n * 16 + lr;
            float bias = b2[e * DIMX + col];
            #pragma unroll
            for (int i = 0; i < 4; i++) {
                int row = wr * 64 + m * 16 + lg * 4 + i;
                float v = (acc[m][n][i] + bias) * s_w[row];
                ybuf[(size_t)(row_base + m0 + row) * DIMX + col] = f2bf(v);
            }
        }
    }
}

// ---------------- combine: out[t] = ybuf[slotA] + ybuf[slotB] ----------------
__global__ __launch_bounds__(256) void combine_kernel(
    const unsigned short* __restrict__ ybuf, const int* __restrict__ tok2slot,
    float* __restrict__ out) {
    int t = blockIdx.x;
    int d = threadIdx.x * 4;
    int sa = tok2slot[t * 2], sb = tok2slot[t * 2 + 1];
    ushort4 a = *(const ushort4*)&ybuf[(size_t)sa * DIMX + d];
    ushort4 b = *(const ushort4*)&ybuf[(size_t)sb * DIMX + d];
    float4 o;
    o.x = bf2f(a.x) + bf2f(b.x);
    o.y = bf2f(a.y) + bf2f(b.y);
    o.z = bf2f(a.z) + bf2f(b.z);
    o.w = bf2f(a.w) + bf2f(b.w);
    *(float4*)&out[(size_t)t * DIMX + d] = o;
}

extern "C" void kernel_launch(void* const* d_in, const int* in_sizes, int n_in,
                              void* d_out, int out_size, void* d_ws, size_t ws_size,
                              hipStream_t stream) {
    const float* x  = (const float*)d_in[0];
    const float* gw = (const float*)d_in[1];
    const float* gb = (const float*)d_in[2];
    const float* W1 = (const float*)d_in[3];
    const float* b1 = (const float*)d_in[4];
    const float* W2 = (const float*)d_in[5];
    const float* b2 = (const float*)d_in[6];
    float* out = (float*)d_out;
    float* logits = out + (size_t)T_TOK * DIMX;

    char* ws = (char*)d_ws;
    unsigned short* W2t = (unsigned short*)ws; ws += (size_t)NE * DIMX * HID * 2;
    // ybuf (P_PAD x DIMX bf16 = 35.7 MB) overlays [W1t | xb] (48 MB), both dead after gemm1.
    unsigned short* W1t = (unsigned short*)ws;
    unsigned short* ybuf = (unsigned short*)ws; ws += (size_t)NE * DIMX * HID * 2;
    unsigned short* xb = (unsigned short*)ws; ws += (size_t)T_TOK * DIMX * 2;
    unsigned short* hbuf = (unsigned short*)ws; ws += (size_t)P_PAD * HID * 2;
    int* counts = (int*)ws; ws += 256;
    int* offsets = (int*)ws; ws += 256;
    int* pair_epos = (int*)ws; ws += (size_t)NPAIR * 4;
    float* pair_w = (float*)ws; ws += (size_t)NPAIR * 4;
    int* slot_token = (int*)ws; ws += (size_t)P_PAD * 4;
    float* slot_weight = (float*)ws; ws += (size_t)P_PAD * 4;
    int* tok2slot = (int*)ws; ws += (size_t)NPAIR * 4;

    init_routing_kernel<<<(P_PAD + 255) / 256, 256, 0, stream>>>(slot_token, slot_weight, counts);
    convx_kernel<<<T_TOK * DIMX / 4 / 256, 256, 0, stream>>>(x, xb);
    conv_transpose_kernel<<<dim3(HID / 64, DIMX / 64, NE), 256, 0, stream>>>(W1, W1t, DIMX, HID);
    conv_transpose_kernel<<<dim3(DIMX / 64, HID / 64, NE), 256, 0, stream>>>(W2, W2t, HID, DIMX);
    gate_kernel<<<T_TOK / GATE_TPB, 256, 0, stream>>>(x, gw, gb, logits, counts, pair_epos, pair_w);
    scan_kernel<<<1, 1, 0, stream>>>(counts, offsets);
    place_kernel<<<NPAIR / 256, 256, 0, stream>>>(pair_epos, pair_w, offsets, slot_token,
                                                  slot_weight, tok2slot);
    // expert on blockIdx.x (gridDim.x=8): flat_id % 8 == expert -> one XCD per expert.
    gemm1_kernel<<<dim3(NE, HID / 128, 128), 256, 0, stream>>>(xb, W1t, b1, offsets, slot_token, hbuf);
    gemm2_kernel<<<dim3(NE, DIMX / 128, 128), 256, 0, stream>>>(hbuf, W2t, b2, offsets, slot_weight, ybuf);
    combine_kernel<<<T_TOK, 256, 0, stream>>>(ybuf, tok2slot, out);
}

// Round 10
// 285.448 us; speedup vs baseline: 1.4049x; 1.4049x over previous
//
#include <hip/hip_runtime.h>
#include <math.h>

#define T_TOK 8192
#define DIMX 1024
#define NE 8
#define HID 2048
#define NPAIR (T_TOK * 2)
#define P_PAD (NPAIR + NE * 128)
#define GATE_TPB 32

typedef __attribute__((ext_vector_type(8))) short s16x8;
typedef __attribute__((ext_vector_type(4))) float f32x4;

static __device__ __forceinline__ unsigned short f2bf(float f) {
    union { float f; unsigned u; } v; v.f = f;
    unsigned r = v.u + 0x7FFFu + ((v.u >> 16) & 1u);
    return (unsigned short)(r >> 16);
}
static __device__ __forceinline__ float bf2f(unsigned short u) {
    union { unsigned u; float f; } v; v.u = (unsigned)u << 16; return v.f;
}

// gelu tanh approximation: v * sigmoid(1.5957691 * v * (1 + 0.044715 v^2))
static __device__ __forceinline__ float gelu_fast(float v) {
    float u2 = -1.5957691216057308f * v * (1.f + 0.044715f * v * v);
    return v * __builtin_amdgcn_rcpf(1.f + __expf(u2));
}

// async global->LDS, 16 bytes per lane. LDS dest must be wave-uniform base + lane*16.
static __device__ __forceinline__ void gload16(const unsigned short* g, unsigned short* l) {
    __builtin_amdgcn_global_load_lds(
        (const __attribute__((address_space(1))) unsigned int*)g,
        (__attribute__((address_space(3))) unsigned int*)l, 16, 0, 0);
}

// ---------------- init: routing slots + counts ----------------
__global__ void init_routing_kernel(int* slot_token, float* slot_weight, int* counts) {
    int i = blockIdx.x * blockDim.x + threadIdx.x;
    if (i < P_PAD) { slot_token[i] = 0; slot_weight[i] = 0.f; }
    if (i < NE) counts[i] = 0;
}

__global__ void convx_kernel(const float* __restrict__ x, unsigned short* __restrict__ xb) {
    int i = blockIdx.x * blockDim.x + threadIdx.x;  // one float4 each
    float4 f = ((const float4*)x)[i];
    unsigned short r[4] = { f2bf(f.x), f2bf(f.y), f2bf(f.z), f2bf(f.w) };
    *(uint2*)&xb[(size_t)i * 4] = *(const uint2*)&r[0];
}

// src [E][R][C] fp32 -> dst [E][C][R] bf16, 64x64 tiles, vectorized both sides
__global__ __launch_bounds__(256) void conv_transpose_kernel(
    const float* __restrict__ src, unsigned short* __restrict__ dst, int R, int C) {
    __shared__ float tile[64][65];
    int e = blockIdx.z;
    int r0 = blockIdx.y * 64, c0 = blockIdx.x * 64;
    const float* s = src + (size_t)e * R * C;
    unsigned short* d = dst + (size_t)e * R * C;
    int tid = threadIdx.x;
    int lr = tid >> 4, lc4 = (tid & 15) * 4;  // 16 rows per pass x 16 float4
    #pragma unroll
    for (int it = 0; it < 4; it++) {
        float4 v = *(const float4*)&s[(size_t)(r0 + it * 16 + lr) * C + c0 + lc4];
        tile[it * 16 + lr][lc4 + 0] = v.x;
        tile[it * 16 + lr][lc4 + 1] = v.y;
        tile[it * 16 + lr][lc4 + 2] = v.z;
        tile[it * 16 + lr][lc4 + 3] = v.w;
    }
    __syncthreads();
    int cc = tid >> 3, rch = (tid & 7) * 8;  // 32 dst rows per pass x 8 chunks of 8
    #pragma unroll
    for (int it = 0; it < 2; it++) {
        int c = it * 32 + cc;
        unsigned short r[8];
        #pragma unroll
        for (int j = 0; j < 8; j++) r[j] = f2bf(tile[rch + j][c]);
        *(uint4*)&d[(size_t)(c0 + c) * R + r0 + rch] = *(const uint4*)&r[0];
    }
}

// ---------------- gating: block-aggregated atomics ----------------
__global__ __launch_bounds__(256) void gate_kernel(
    const float* __restrict__ x, const float* __restrict__ gw, const float* __restrict__ gb,
    float* __restrict__ logits_out, int* counts, int* __restrict__ pair_epos,
    float* __restrict__ pair_w) {
    __shared__ float sgw[NE * DIMX];
    __shared__ int lcount[NE], lbase[NE];
    __shared__ int s_e[GATE_TPB * 2];
    __shared__ int s_lp[GATE_TPB * 2];
    __shared__ float s_wv[GATE_TPB * 2];
    int tid = threadIdx.x;
    for (int i = tid; i < NE * DIMX / 4; i += 256)
        ((float4*)sgw)[i] = ((const float4*)gw)[i];
    if (tid < NE) lcount[tid] = 0;
    __syncthreads();

    int wave = tid >> 6, lane = tid & 63;
    int tbase = blockIdx.x * GATE_TPB;
    for (int r = 0; r < GATE_TPB / 4; ++r) {
        int ti = wave * (GATE_TPB / 4) + r;
        int t = tbase + ti;
        const float* xr = x + (size_t)t * DIMX;
        float acc[NE] = {};
        #pragma unroll
        for (int i = 0; i < DIMX / 256; i++) {
            float4 xv = *(const float4*)&xr[i * 256 + lane * 4];
            #pragma unroll
            for (int e = 0; e < NE; e++) {
                float4 wv = *(const float4*)&sgw[e * DIMX + i * 256 + lane * 4];
                acc[e] += xv.x * wv.x + xv.y * wv.y + xv.z * wv.z + xv.w * wv.w;
            }
        }
        #pragma unroll
        for (int e = 0; e < NE; e++) {
            #pragma unroll
            for (int off = 32; off; off >>= 1) acc[e] += __shfl_xor(acc[e], off);
        }
        if (lane == 0) {
            float* lo = logits_out + (size_t)t * NE;
            #pragma unroll
            for (int e = 0; e < NE; e++) { acc[e] += gb[e]; lo[e] = acc[e]; }
            // top-2 (strict > keeps lowest index on ties, matching jax.lax.top_k)
            float l0 = acc[0]; int e0 = 0;
            #pragma unroll
            for (int e = 1; e < NE; e++) if (acc[e] > l0) { l0 = acc[e]; e0 = e; }
            float l1 = -1e30f; int e1 = -1;
            #pragma unroll
            for (int e = 0; e < NE; e++) if (e != e0 && acc[e] > l1) { l1 = acc[e]; e1 = e; }
            float q = expf(l1 - l0);
            float wn0 = 1.f / (1.f + q);
            float wn1 = q / (1.f + q);
            int lp0 = atomicAdd(&lcount[e0], 1);
            int lp1 = atomicAdd(&lcount[e1], 1);
            s_e[ti * 2] = e0; s_lp[ti * 2] = lp0; s_wv[ti * 2] = wn0;
            s_e[ti * 2 + 1] = e1; s_lp[ti * 2 + 1] = lp1; s_wv[ti * 2 + 1] = wn1;
        }
    }
    __syncthreads();
    if (tid < NE) lbase[tid] = atomicAdd(&counts[tid], lcount[tid]);
    __syncthreads();
    if (tid < GATE_TPB * 2) {
        int e = s_e[tid];
        int gp = lbase[e] + s_lp[tid];
        int gi = (tbase + (tid >> 1)) * 2 + (tid & 1);
        pair_epos[gi] = (e << 28) | gp;
        pair_w[gi] = s_wv[tid];
    }
}

__global__ void scan_kernel(const int* counts, int* offsets) {
    if (threadIdx.x == 0 && blockIdx.x == 0) {
        int o = 0;
        offsets[0] = 0;
        for (int e = 0; e < NE; e++) { o += (counts[e] + 127) & ~127; offsets[e + 1] = o; }
    }
}

__global__ void place_kernel(const int* __restrict__ pair_epos, const float* __restrict__ pair_w,
                             const int* __restrict__ offsets, int* __restrict__ slot_token,
                             float* __restrict__ slot_weight, int* __restrict__ tok2slot) {
    int p = blockIdx.x * 256 + threadIdx.x;
    if (p >= NPAIR) return;
    int ep = pair_epos[p];
    int e = ep >> 28;
    int pos = ep & 0x0FFFFFFF;
    int slot = offsets[e] + pos;
    slot_token[slot] = p >> 1;
    slot_weight[slot] = pair_w[p];
    tok2slot[p] = slot;
}

// shared pipeline pieces: 3-buffer LDS, stage depth 2, counted vmcnt, raw barriers.
#define BARRIER() asm volatile("s_barrier" ::: "memory")
#define WAIT_VM(n) asm volatile("s_waitcnt vmcnt(" #n ")" ::: "memory")
#define WAIT_LGKM0() do { asm volatile("s_waitcnt lgkmcnt(0)" ::: "memory"); \
                          __builtin_amdgcn_sched_barrier(0); } while (0)

// Swizzled LDS tile layout (both operands), 512 chunks of 16B per 128x32 tile:
//   slot c holds global chunk (row = c>>2, kseg = (c&3) ^ ((c>>3)&3)).
// Write: thread tid -> slots tid, tid+256: row tid>>2 (+64), kseg (tid&3)^((tid>>3)&3);
//   4 lanes per row cover one contiguous 64B segment (permuted) -> fully coalesced.
// Read: fragment (row, kseg=lg) at slot row*4 + (lg ^ ((row>>1)&3)); fragment bases are
//   multiples of 16 so the XOR term is lane-constant kx = lg^((lr>>1)&3); banks spread
//   over 8 quad-bank slots x 8 lanes = 2-way aliasing = conflict-free.

// ---------------- grouped GEMM 1: h = gelu(x @ W1 + b1) ----------------
// grid (8=expert, Nn, Nm): expert on blockIdx.x pins expert e -> XCD e (flat%8).
__global__ __launch_bounds__(256) void gemm1_kernel(
    const unsigned short* __restrict__ xb, const unsigned short* __restrict__ W1t,
    const float* __restrict__ b1, const int* __restrict__ offsets,
    const int* __restrict__ slot_token, unsigned short* __restrict__ hbuf) {
    int e = blockIdx.x;
    int row_base = offsets[e];
    int rows = offsets[e + 1] - row_base;
    int m0 = blockIdx.z * 128;
    if (m0 >= rows) return;
    int n0 = blockIdx.y * 128;

    __shared__ unsigned short sA[3][128 * 32];
    __shared__ unsigned short sB[3][128 * 32];

    int tid = threadIdx.x;
    const unsigned short* w1e = W1t + (size_t)e * HID * DIMX;

    int srow = tid >> 2;
    int kperm = (tid & 3) ^ ((tid >> 3) & 3);
    int tok0 = slot_token[row_base + m0 + srow];
    int tok1 = slot_token[row_base + m0 + srow + 64];
    const unsigned short* gA0 = xb + (size_t)tok0 * DIMX + kperm * 8;
    const unsigned short* gA1 = xb + (size_t)tok1 * DIMX + kperm * 8;
    const unsigned short* gB0 = w1e + (size_t)(n0 + srow) * DIMX + kperm * 8;
    const unsigned short* gB1 = w1e + (size_t)(n0 + srow + 64) * DIMX + kperm * 8;

#define STG1(b, k0) do { \
        gload16(gA0 + (k0), &sA[b][tid * 8]); \
        gload16(gA1 + (k0), &sA[b][(tid + 256) * 8]); \
        gload16(gB0 + (k0), &sB[b][tid * 8]); \
        gload16(gB1 + (k0), &sB[b][(tid + 256) * 8]); \
    } while (0)

    f32x4 acc[4][4] = {};
    int wv = tid >> 6; int wr = wv >> 1, wc = wv & 1;
    int lane = tid & 63; int lr = lane & 15, lg = lane >> 4;
    int kx8 = (lg ^ ((lr >> 1) & 3)) * 8;

#define CMP1(CUR) do { \
        s16x8 af[4], bfr[4]; \
        _Pragma("unroll") \
        for (int m = 0; m < 4; m++) af[m] = *(const s16x8*)&sA[CUR][(wr * 64 + m * 16 + lr) * 32 + kx8]; \
        _Pragma("unroll") \
        for (int n = 0; n < 4; n++) bfr[n] = *(const s16x8*)&sB[CUR][(wc * 64 + n * 16 + lr) * 32 + kx8]; \
        __builtin_amdgcn_s_setprio(1); \
        _Pragma("unroll") \
        for (int m = 0; m < 4; m++) { \
            _Pragma("unroll") \
            for (int n = 0; n < 4; n++) \
                acc[m][n] = __builtin_amdgcn_mfma_f32_16x16x32_bf16(af[m], bfr[n], acc[m][n], 0, 0, 0); \
        } \
        __builtin_amdgcn_s_setprio(0); \
    } while (0)

    const int NT = DIMX / 32;
    STG1(0, 0);
    STG1(1, 32);
    int cur = 0;
    for (int t = 0; t < NT - 2; ++t) {
        int nxt = cur + 2; if (nxt >= 3) nxt -= 3;
        STG1(nxt, (t + 2) * 32);
        WAIT_VM(8);
        BARRIER();
        CMP1(cur);
        WAIT_LGKM0();
        BARRIER();
        cur = (cur + 1 == 3) ? 0 : cur + 1;
    }
    WAIT_VM(4);
    BARRIER();
    CMP1(cur);
    WAIT_LGKM0();
    BARRIER();
    cur = (cur + 1 == 3) ? 0 : cur + 1;
    WAIT_VM(0);
    BARRIER();
    CMP1(cur);
#undef STG1
#undef CMP1

    #pragma unroll
    for (int m = 0; m < 4; m++) {
        #pragma unroll
        for (int n = 0; n < 4; n++) {
            int col = n0 + wc * 64 + n * 16 + lr;
            float bias = b1[e * HID + col];
            #pragma unroll
            for (int i = 0; i < 4; i++) {
                int row = wr * 64 + m * 16 + lg * 4 + i;
                float v = gelu_fast(acc[m][n][i] + bias);
                hbuf[(size_t)(row_base + m0 + row) * HID + col] = f2bf(v);
            }
        }
    }
}

// ---------------- grouped GEMM 2: ybuf[slot] = w * (h @ W2 + b2), plain stores ----------------
__global__ __launch_bounds__(256) void gemm2_kernel(
    const unsigned short* __restrict__ hbuf, const unsigned short* __restrict__ W2t,
    const float* __restrict__ b2, const int* __restrict__ offsets,
    const float* __restrict__ slot_weight, unsigned short* __restrict__ ybuf) {
    int e = blockIdx.x;
    int row_base = offsets[e];
    int rows = offsets[e + 1] - row_base;
    int m0 = blockIdx.z * 128;
    if (m0 >= rows) return;
    int n0 = blockIdx.y * 128;

    __shared__ unsigned short sA[3][128 * 32];
    __shared__ unsigned short sB[3][128 * 32];
    __shared__ float s_w[128];

    int tid = threadIdx.x;
    if (tid < 128) s_w[tid] = slot_weight[row_base + m0 + tid];

    const unsigned short* ha = hbuf + (size_t)(row_base + m0) * HID;
    const unsigned short* w2e = W2t + (size_t)e * DIMX * HID;

    int srow = tid >> 2;
    int kperm = (tid & 3) ^ ((tid >> 3) & 3);
    const unsigned short* gA0 = ha + (size_t)srow * HID + kperm * 8;
    const unsigned short* gA1 = ha + (size_t)(srow + 64) * HID + kperm * 8;
    const unsigned short* gB0 = w2e + (size_t)(n0 + srow) * HID + kperm * 8;
    const unsigned short* gB1 = w2e + (size_t)(n0 + srow + 64) * HID + kperm * 8;

#define STG2(b, k0) do { \
        gload16(gA0 + (k0), &sA[b][tid * 8]); \
        gload16(gA1 + (k0), &sA[b][(tid + 256) * 8]); \
        gload16(gB0 + (k0), &sB[b][tid * 8]); \
        gload16(gB1 + (k0), &sB[b][(tid + 256) * 8]); \
    } while (0)

    f32x4 acc[4][4] = {};
    int wv = tid >> 6; int wr = wv >> 1, wc = wv & 1;
    int lane = tid & 63; int lr = lane & 15, lg = lane >> 4;
    int kx8 = (lg ^ ((lr >> 1) & 3)) * 8;

#define CMP2(CUR) do { \
        s16x8 af[4], bfr[4]; \
        _Pragma("unroll") \
        for (int m = 0; m < 4; m++) af[m] = *(const s16x8*)&sA[CUR][(wr * 64 + m * 16 + lr) * 32 + kx8]; \
        _Pragma("unroll") \
        for (int n = 0; n < 4; n++) bfr[n] = *(const s16x8*)&sB[CUR][(wc * 64 + n * 16 + lr) * 32 + kx8]; \
        __builtin_amdgcn_s_setprio(1); \
        _Pragma("unroll") \
        for (int m = 0; m < 4; m++) { \
            _Pragma("unroll") \
            for (int n = 0; n < 4; n++) \
                acc[m][n] = __builtin_amdgcn_mfma_f32_16x16x32_bf16(af[m], bfr[n], acc[m][n], 0, 0, 0); \
        } \
        __builtin_amdgcn_s_setprio(0); \
    } while (0)

    const int NT = HID / 32;
    STG2(0, 0);
    STG2(1, 32);
    int cur = 0;
    for (int t = 0; t < NT - 2; ++t) {
        int nxt = cur + 2; if (nxt >= 3) nxt -= 3;
        STG2(nxt, (t + 2) * 32);
        WAIT_VM(8);
        BARRIER();
        CMP2(cur);
        WAIT_LGKM0();
        BARRIER();
        cur = (cur + 1 == 3) ? 0 : cur + 1;
    }
    WAIT_VM(4);
    BARRIER();
    CMP2(cur);
    WAIT_LGKM0();
    BARRIER();
    cur = (cur + 1 == 3) ? 0 : cur + 1;
    WAIT_VM(0);
    BARRIER();
    CMP2(cur);
#undef STG2
#undef CMP2

    #pragma unroll
    for (int m = 0; m < 4; m++) {
        #pragma unroll
        for (int n = 0; n < 4; n++) {
            int col = n0 + wc * 64 + n * 16 + lr;
            float bias = b2[e * DIMX + col];
            #pragma unroll
            for (int i = 0; i < 4; i++) {
                int row = wr * 64 + m * 16 + lg * 4 + i;
                float v = (acc[m][n][i] + bias) * s_w[row];
                ybuf[(size_t)(row_base + m0 + row) * DIMX + col] = f2bf(v);
            }
        }
    }
}

// ---------------- combine: out[t] = ybuf[slotA] + ybuf[slotB] ----------------
__global__ __launch_bounds__(256) void combine_kernel(
    const unsigned short* __restrict__ ybuf, const int* __restrict__ tok2slot,
    float* __restrict__ out) {
    int t = blockIdx.x;
    int d = threadIdx.x * 4;
    int sa = tok2slot[t * 2], sb = tok2slot[t * 2 + 1];
    ushort4 a = *(const ushort4*)&ybuf[(size_t)sa * DIMX + d];
    ushort4 b = *(const ushort4*)&ybuf[(size_t)sb * DIMX + d];
    float4 o;
    o.x = bf2f(a.x) + bf2f(b.x);
    o.y = bf2f(a.y) + bf2f(b.y);
    o.z = bf2f(a.z) + bf2f(b.z);
    o.w = bf2f(a.w) + bf2f(b.w);
    *(float4*)&out[(size_t)t * DIMX + d] = o;
}

extern "C" void kernel_launch(void* const* d_in, const int* in_sizes, int n_in,
                              void* d_out, int out_size, void* d_ws, size_t ws_size,
                              hipStream_t stream) {
    const float* x  = (const float*)d_in[0];
    const float* gw = (const float*)d_in[1];
    const float* gb = (const float*)d_in[2];
    const float* W1 = (const float*)d_in[3];
    const float* b1 = (const float*)d_in[4];
    const float* W2 = (const float*)d_in[5];
    const float* b2 = (const float*)d_in[6];
    float* out = (float*)d_out;
    float* logits = out + (size_t)T_TOK * DIMX;

    char* ws = (char*)d_ws;
    unsigned short* W2t = (unsigned short*)ws; ws += (size_t)NE * DIMX * HID * 2;
    // ybuf (P_PAD x DIMX bf16 = 35.7 MB) overlays [W1t | xb] (48 MB), both dead after gemm1.
    unsigned short* W1t = (unsigned short*)ws;
    unsigned short* ybuf = (unsigned short*)ws; ws += (size_t)NE * DIMX * HID * 2;
    unsigned short* xb = (unsigned short*)ws; ws += (size_t)T_TOK * DIMX * 2;
    unsigned short* hbuf = (unsigned short*)ws; ws += (size_t)P_PAD * HID * 2;
    int* counts = (int*)ws; ws += 256;
    int* offsets = (int*)ws; ws += 256;
    int* pair_epos = (int*)ws; ws += (size_t)NPAIR * 4;
    float* pair_w = (float*)ws; ws += (size_t)NPAIR * 4;
    int* slot_token = (int*)ws; ws += (size_t)P_PAD * 4;
    float* slot_weight = (float*)ws; ws += (size_t)P_PAD * 4;
    int* tok2slot = (int*)ws; ws += (size_t)NPAIR * 4;

    init_routing_kernel<<<(P_PAD + 255) / 256, 256, 0, stream>>>(slot_token, slot_weight, counts);
    convx_kernel<<<T_TOK * DIMX / 4 / 256, 256, 0, stream>>>(x, xb);
    conv_transpose_kernel<<<dim3(HID / 64, DIMX / 64, NE), 256, 0, stream>>>(W1, W1t, DIMX, HID);
    conv_transpose_kernel<<<dim3(DIMX / 64, HID / 64, NE), 256, 0, stream>>>(W2, W2t, HID, DIMX);
    gate_kernel<<<T_TOK / GATE_TPB, 256, 0, stream>>>(x, gw, gb, logits, counts, pair_epos, pair_w);
    scan_kernel<<<1, 1, 0, stream>>>(counts, offsets);
    place_kernel<<<NPAIR / 256, 256, 0, stream>>>(pair_epos, pair_w, offsets, slot_token,
                                                  slot_weight, tok2slot);
    // expert on blockIdx.x (gridDim.x=8): flat_id % 8 == expert -> one XCD per expert.
    gemm1_kernel<<<dim3(NE, HID / 128, 128), 256, 0, stream>>>(xb, W1t, b1, offsets, slot_token, hbuf);
    gemm2_kernel<<<dim3(NE, DIMX / 128, 128), 256, 0, stream>>>(hbuf, W2t, b2, offsets, slot_weight, ybuf);
    combine_kernel<<<T_TOK, 256, 0, stream>>>(ybuf, tok2slot, out);
}

// Round 11
// 281.034 us; speedup vs baseline: 1.4269x; 1.0157x over previous
//
#include <hip/hip_runtime.h>
#include <math.h>

#define T_TOK 8192
#define DIMX 1024
#define NE 8
#define HID 2048
#define NPAIR (T_TOK * 2)
#define P_PAD (NPAIR + NE * 128)
#define GATE_TPB 32

typedef __attribute__((ext_vector_type(8))) short s16x8;
typedef __attribute__((ext_vector_type(4))) float f32x4;

static __device__ __forceinline__ unsigned short f2bf(float f) {
    union { float f; unsigned u; } v; v.f = f;
    unsigned r = v.u + 0x7FFFu + ((v.u >> 16) & 1u);
    return (unsigned short)(r >> 16);
}
static __device__ __forceinline__ float bf2f(unsigned short u) {
    union { unsigned u; float f; } v; v.u = (unsigned)u << 16; return v.f;
}

// gelu tanh approximation: v * sigmoid(1.5957691 * v * (1 + 0.044715 v^2))
static __device__ __forceinline__ float gelu_fast(float v) {
    float u2 = -1.5957691216057308f * v * (1.f + 0.044715f * v * v);
    return v * __builtin_amdgcn_rcpf(1.f + __expf(u2));
}

// async global->LDS, 16 bytes per lane. LDS dest must be wave-uniform base + lane*16.
static __device__ __forceinline__ void gload16(const unsigned short* g, unsigned short* l) {
    __builtin_amdgcn_global_load_lds(
        (const __attribute__((address_space(1))) unsigned int*)g,
        (__attribute__((address_space(3))) unsigned int*)l, 16, 0, 0);
}

// ---------------- init: routing slots + counts ----------------
__global__ void init_routing_kernel(int* slot_token, float* slot_weight, int* counts) {
    int i = blockIdx.x * blockDim.x + threadIdx.x;
    if (i < P_PAD) { slot_token[i] = 0; slot_weight[i] = 0.f; }
    if (i < NE) counts[i] = 0;
}

// src [E][R][C] fp32 -> dst [E][C][R] bf16, 64x64 tiles, vectorized both sides
__global__ __launch_bounds__(256) void conv_transpose_kernel(
    const float* __restrict__ src, unsigned short* __restrict__ dst, int R, int C) {
    __shared__ float tile[64][65];
    int e = blockIdx.z;
    int r0 = blockIdx.y * 64, c0 = blockIdx.x * 64;
    const float* s = src + (size_t)e * R * C;
    unsigned short* d = dst + (size_t)e * R * C;
    int tid = threadIdx.x;
    int lr = tid >> 4, lc4 = (tid & 15) * 4;  // 16 rows per pass x 16 float4
    #pragma unroll
    for (int it = 0; it < 4; it++) {
        float4 v = *(const float4*)&s[(size_t)(r0 + it * 16 + lr) * C + c0 + lc4];
        tile[it * 16 + lr][lc4 + 0] = v.x;
        tile[it * 16 + lr][lc4 + 1] = v.y;
        tile[it * 16 + lr][lc4 + 2] = v.z;
        tile[it * 16 + lr][lc4 + 3] = v.w;
    }
    __syncthreads();
    int cc = tid >> 3, rch = (tid & 7) * 8;  // 32 dst rows per pass x 8 chunks of 8
    #pragma unroll
    for (int it = 0; it < 2; it++) {
        int c = it * 32 + cc;
        unsigned short r[8];
        #pragma unroll
        for (int j = 0; j < 8; j++) r[j] = f2bf(tile[rch + j][c]);
        *(uint4*)&d[(size_t)(c0 + c) * R + r0 + rch] = *(const uint4*)&r[0];
    }
}

// ---------------- gating: block-aggregated atomics; also emits xb (bf16 x) ----------------
__global__ __launch_bounds__(256) void gate_kernel(
    const float* __restrict__ x, const float* __restrict__ gw, const float* __restrict__ gb,
    float* __restrict__ logits_out, int* counts, int* __restrict__ pair_epos,
    float* __restrict__ pair_w, unsigned short* __restrict__ xb) {
    __shared__ float sgw[NE * DIMX];
    __shared__ int lcount[NE], lbase[NE];
    __shared__ int s_e[GATE_TPB * 2];
    __shared__ int s_lp[GATE_TPB * 2];
    __shared__ float s_wv[GATE_TPB * 2];
    int tid = threadIdx.x;
    for (int i = tid; i < NE * DIMX / 4; i += 256)
        ((float4*)sgw)[i] = ((const float4*)gw)[i];
    if (tid < NE) lcount[tid] = 0;
    __syncthreads();

    int wave = tid >> 6, lane = tid & 63;
    int tbase = blockIdx.x * GATE_TPB;
    for (int r = 0; r < GATE_TPB / 4; ++r) {
        int ti = wave * (GATE_TPB / 4) + r;
        int t = tbase + ti;
        const float* xr = x + (size_t)t * DIMX;
        float acc[NE] = {};
        #pragma unroll
        for (int i = 0; i < DIMX / 256; i++) {
            float4 xv = *(const float4*)&xr[i * 256 + lane * 4];
            // fold convx: emit bf16 copy of x while it's in registers
            unsigned short rb[4] = { f2bf(xv.x), f2bf(xv.y), f2bf(xv.z), f2bf(xv.w) };
            *(uint2*)&xb[(size_t)t * DIMX + i * 256 + lane * 4] = *(const uint2*)&rb[0];
            #pragma unroll
            for (int e = 0; e < NE; e++) {
                float4 wv = *(const float4*)&sgw[e * DIMX + i * 256 + lane * 4];
                acc[e] += xv.x * wv.x + xv.y * wv.y + xv.z * wv.z + xv.w * wv.w;
            }
        }
        #pragma unroll
        for (int e = 0; e < NE; e++) {
            #pragma unroll
            for (int off = 32; off; off >>= 1) acc[e] += __shfl_xor(acc[e], off);
        }
        if (lane == 0) {
            float* lo = logits_out + (size_t)t * NE;
            #pragma unroll
            for (int e = 0; e < NE; e++) { acc[e] += gb[e]; lo[e] = acc[e]; }
            // top-2 (strict > keeps lowest index on ties, matching jax.lax.top_k)
            float l0 = acc[0]; int e0 = 0;
            #pragma unroll
            for (int e = 1; e < NE; e++) if (acc[e] > l0) { l0 = acc[e]; e0 = e; }
            float l1 = -1e30f; int e1 = -1;
            #pragma unroll
            for (int e = 0; e < NE; e++) if (e != e0 && acc[e] > l1) { l1 = acc[e]; e1 = e; }
            float q = expf(l1 - l0);
            float wn0 = 1.f / (1.f + q);
            float wn1 = q / (1.f + q);
            int lp0 = atomicAdd(&lcount[e0], 1);
            int lp1 = atomicAdd(&lcount[e1], 1);
            s_e[ti * 2] = e0; s_lp[ti * 2] = lp0; s_wv[ti * 2] = wn0;
            s_e[ti * 2 + 1] = e1; s_lp[ti * 2 + 1] = lp1; s_wv[ti * 2 + 1] = wn1;
        }
    }
    __syncthreads();
    if (tid < NE) lbase[tid] = atomicAdd(&counts[tid], lcount[tid]);
    __syncthreads();
    if (tid < GATE_TPB * 2) {
        int e = s_e[tid];
        int gp = lbase[e] + s_lp[tid];
        int gi = (tbase + (tid >> 1)) * 2 + (tid & 1);
        pair_epos[gi] = (e << 28) | gp;
        pair_w[gi] = s_wv[tid];
    }
}

__global__ void scan_kernel(const int* counts, int* offsets) {
    if (threadIdx.x == 0 && blockIdx.x == 0) {
        int o = 0;
        offsets[0] = 0;
        for (int e = 0; e < NE; e++) { o += (counts[e] + 127) & ~127; offsets[e + 1] = o; }
    }
}

__global__ void place_kernel(const int* __restrict__ pair_epos, const float* __restrict__ pair_w,
                             const int* __restrict__ offsets, int* __restrict__ slot_token,
                             float* __restrict__ slot_weight, int* __restrict__ tok2slot) {
    int p = blockIdx.x * 256 + threadIdx.x;
    if (p >= NPAIR) return;
    int ep = pair_epos[p];
    int e = ep >> 28;
    int pos = ep & 0x0FFFFFFF;
    int slot = offsets[e] + pos;
    slot_token[slot] = p >> 1;
    slot_weight[slot] = pair_w[p];
    tok2slot[p] = slot;
}

// pipeline: 2-buffer LDS (32 KB -> ~5 blocks/CU), depth-1 prefetch, counted vmcnt.
#define BARRIER() asm volatile("s_barrier" ::: "memory")
#define WAIT_VM(n) asm volatile("s_waitcnt vmcnt(" #n ")" ::: "memory")
#define WAIT_LGKM0() do { asm volatile("s_waitcnt lgkmcnt(0)" ::: "memory"); \
                          __builtin_amdgcn_sched_barrier(0); } while (0)

// Swizzled LDS tile layout (both operands), 512 chunks of 16B per 128x32 tile:
//   slot c holds global chunk (row = c>>2, kseg = (c&3) ^ ((c>>3)&3)).
// Write: coalesced (4 lanes per row cover one contiguous permuted 64B segment).
// Read: fragment kseg=lg at lane-constant kx = lg^((lr>>1)&3) -> conflict-free.

// ---------------- grouped GEMM 1: h = gelu(x @ W1 + b1) ----------------
// grid (8=expert, Nn, Nm): expert on blockIdx.x pins expert e -> XCD e (flat%8).
__global__ __launch_bounds__(256) void gemm1_kernel(
    const unsigned short* __restrict__ xb, const unsigned short* __restrict__ W1t,
    const float* __restrict__ b1, const int* __restrict__ offsets,
    const int* __restrict__ slot_token, unsigned short* __restrict__ hbuf) {
    int e = blockIdx.x;
    int row_base = offsets[e];
    int rows = offsets[e + 1] - row_base;
    int m0 = blockIdx.z * 128;
    if (m0 >= rows) return;
    int n0 = blockIdx.y * 128;

    __shared__ unsigned short sA[2][128 * 32];
    __shared__ unsigned short sB[2][128 * 32];

    int tid = threadIdx.x;
    const unsigned short* w1e = W1t + (size_t)e * HID * DIMX;

    int srow = tid >> 2;
    int kperm = (tid & 3) ^ ((tid >> 3) & 3);
    int tok0 = slot_token[row_base + m0 + srow];
    int tok1 = slot_token[row_base + m0 + srow + 64];
    const unsigned short* gA0 = xb + (size_t)tok0 * DIMX + kperm * 8;
    const unsigned short* gA1 = xb + (size_t)tok1 * DIMX + kperm * 8;
    const unsigned short* gB0 = w1e + (size_t)(n0 + srow) * DIMX + kperm * 8;
    const unsigned short* gB1 = w1e + (size_t)(n0 + srow + 64) * DIMX + kperm * 8;

#define STG1(b, k0) do { \
        gload16(gA0 + (k0), &sA[b][tid * 8]); \
        gload16(gA1 + (k0), &sA[b][(tid + 256) * 8]); \
        gload16(gB0 + (k0), &sB[b][tid * 8]); \
        gload16(gB1 + (k0), &sB[b][(tid + 256) * 8]); \
    } while (0)

    f32x4 acc[4][4] = {};
    int wv = tid >> 6; int wr = wv >> 1, wc = wv & 1;
    int lane = tid & 63; int lr = lane & 15, lg = lane >> 4;
    int kx8 = (lg ^ ((lr >> 1) & 3)) * 8;

#define CMP1(CUR) do { \
        s16x8 af[4], bfr[4]; \
        _Pragma("unroll") \
        for (int m = 0; m < 4; m++) af[m] = *(const s16x8*)&sA[CUR][(wr * 64 + m * 16 + lr) * 32 + kx8]; \
        _Pragma("unroll") \
        for (int n = 0; n < 4; n++) bfr[n] = *(const s16x8*)&sB[CUR][(wc * 64 + n * 16 + lr) * 32 + kx8]; \
        __builtin_amdgcn_s_setprio(1); \
        _Pragma("unroll") \
        for (int m = 0; m < 4; m++) { \
            _Pragma("unroll") \
            for (int n = 0; n < 4; n++) \
                acc[m][n] = __builtin_amdgcn_mfma_f32_16x16x32_bf16(af[m], bfr[n], acc[m][n], 0, 0, 0); \
        } \
        __builtin_amdgcn_s_setprio(0); \
    } while (0)

    const int NT = DIMX / 32;
    STG1(0, 0);
    int cur = 0;
    for (int t = 0; t < NT - 1; ++t) {
        STG1(cur ^ 1, (t + 1) * 32);
        WAIT_VM(4);       // drain my 4 loads for tile t; t+1's stay in flight
        BARRIER();
        CMP1(cur);
        WAIT_LGKM0();     // my ds_reads of buf[cur] complete
        BARRIER();        // all waves done reading -> buf[cur] reusable next iter
        cur ^= 1;
    }
    WAIT_VM(0);
    BARRIER();
    CMP1(cur);
#undef STG1
#undef CMP1

    #pragma unroll
    for (int m = 0; m < 4; m++) {
        #pragma unroll
        for (int n = 0; n < 4; n++) {
            int col = n0 + wc * 64 + n * 16 + lr;
            float bias = b1[e * HID + col];
            #pragma unroll
            for (int i = 0; i < 4; i++) {
                int row = wr * 64 + m * 16 + lg * 4 + i;
                float v = gelu_fast(acc[m][n][i] + bias);
                hbuf[(size_t)(row_base + m0 + row) * HID + col] = f2bf(v);
            }
        }
    }
}

// ---------------- grouped GEMM 2: ybuf[slot] = w * (h @ W2 + b2), plain stores ----------------
__global__ __launch_bounds__(256) void gemm2_kernel(
    const unsigned short* __restrict__ hbuf, const unsigned short* __restrict__ W2t,
    const float* __restrict__ b2, const int* __restrict__ offsets,
    const float* __restrict__ slot_weight, unsigned short* __restrict__ ybuf) {
    int e = blockIdx.x;
    int row_base = offsets[e];
    int rows = offsets[e + 1] - row_base;
    int m0 = blockIdx.z * 128;
    if (m0 >= rows) return;
    int n0 = blockIdx.y * 128;

    __shared__ unsigned short sA[2][128 * 32];
    __shared__ unsigned short sB[2][128 * 32];
    __shared__ float s_w[128];

    int tid = threadIdx.x;
    if (tid < 128) s_w[tid] = slot_weight[row_base + m0 + tid];

    const unsigned short* ha = hbuf + (size_t)(row_base + m0) * HID;
    const unsigned short* w2e = W2t + (size_t)e * DIMX * HID;

    int srow = tid >> 2;
    int kperm = (tid & 3) ^ ((tid >> 3) & 3);
    const unsigned short* gA0 = ha + (size_t)srow * HID + kperm * 8;
    const unsigned short* gA1 = ha + (size_t)(srow + 64) * HID + kperm * 8;
    const unsigned short* gB0 = w2e + (size_t)(n0 + srow) * HID + kperm * 8;
    const unsigned short* gB1 = w2e + (size_t)(n0 + srow + 64) * HID + kperm * 8;

#define STG2(b, k0) do { \
        gload16(gA0 + (k0), &sA[b][tid * 8]); \
        gload16(gA1 + (k0), &sA[b][(tid + 256) * 8]); \
        gload16(gB0 + (k0), &sB[b][tid * 8]); \
        gload16(gB1 + (k0), &sB[b][(tid + 256) * 8]); \
    } while (0)

    f32x4 acc[4][4] = {};
    int wv = tid >> 6; int wr = wv >> 1, wc = wv & 1;
    int lane = tid & 63; int lr = lane & 15, lg = lane >> 4;
    int kx8 = (lg ^ ((lr >> 1) & 3)) * 8;

#define CMP2(CUR) do { \
        s16x8 af[4], bfr[4]; \
        _Pragma("unroll") \
        for (int m = 0; m < 4; m++) af[m] = *(const s16x8*)&sA[CUR][(wr * 64 + m * 16 + lr) * 32 + kx8]; \
        _Pragma("unroll") \
        for (int n = 0; n < 4; n++) bfr[n] = *(const s16x8*)&sB[CUR][(wc * 64 + n * 16 + lr) * 32 + kx8]; \
        __builtin_amdgcn_s_setprio(1); \
        _Pragma("unroll") \
        for (int m = 0; m < 4; m++) { \
            _Pragma("unroll") \
            for (int n = 0; n < 4; n++) \
                acc[m][n] = __builtin_amdgcn_mfma_f32_16x16x32_bf16(af[m], bfr[n], acc[m][n], 0, 0, 0); \
        } \
        __builtin_amdgcn_s_setprio(0); \
    } while (0)

    const int NT = HID / 32;
    STG2(0, 0);
    int cur = 0;
    for (int t = 0; t < NT - 1; ++t) {
        STG2(cur ^ 1, (t + 1) * 32);
        WAIT_VM(4);
        BARRIER();
        CMP2(cur);
        WAIT_LGKM0();
        BARRIER();
        cur ^= 1;
    }
    WAIT_VM(0);
    BARRIER();
    CMP2(cur);
#undef STG2
#undef CMP2

    #pragma unroll
    for (int m = 0; m < 4; m++) {
        #pragma unroll
        for (int n = 0; n < 4; n++) {
            int col = n0 + wc * 64 + n * 16 + lr;
            float bias = b2[e * DIMX + col];
            #pragma unroll
            for (int i = 0; i < 4; i++) {
                int row = wr * 64 + m * 16 + lg * 4 + i;
                float v = (acc[m][n][i] + bias) * s_w[row];
                ybuf[(size_t)(row_base + m0 + row) * DIMX + col] = f2bf(v);
            }
        }
    }
}

// ---------------- combine: out[t] = ybuf[slotA] + ybuf[slotB] ----------------
__global__ __launch_bounds__(256) void combine_kernel(
    const unsigned short* __restrict__ ybuf, const int* __restrict__ tok2slot,
    float* __restrict__ out) {
    int t = blockIdx.x;
    int d = threadIdx.x * 4;
    int sa = tok2slot[t * 2], sb = tok2slot[t * 2 + 1];
    ushort4 a = *(const ushort4*)&ybuf[(size_t)sa * DIMX + d];
    ushort4 b = *(const ushort4*)&ybuf[(size_t)sb * DIMX + d];
    float4 o;
    o.x = bf2f(a.x) + bf2f(b.x);
    o.y = bf2f(a.y) + bf2f(b.y);
    o.z = bf2f(a.z) + bf2f(b.z);
    o.w = bf2f(a.w) + bf2f(b.w);
    *(float4*)&out[(size_t)t * DIMX + d] = o;
}

extern "C" void kernel_launch(void* const* d_in, const int* in_sizes, int n_in,
                              void* d_out, int out_size, void* d_ws, size_t ws_size,
                              hipStream_t stream) {
    const float* x  = (const float*)d_in[0];
    const float* gw = (const float*)d_in[1];
    const float* gb = (const float*)d_in[2];
    const float* W1 = (const float*)d_in[3];
    const float* b1 = (const float*)d_in[4];
    const float* W2 = (const float*)d_in[5];
    const float* b2 = (const float*)d_in[6];
    float* out = (float*)d_out;
    float* logits = out + (size_t)T_TOK * DIMX;

    char* ws = (char*)d_ws;
    unsigned short* W2t = (unsigned short*)ws; ws += (size_t)NE * DIMX * HID * 2;
    // ybuf (P_PAD x DIMX bf16 = 35.7 MB) overlays [W1t | xb] (48 MB), both dead after gemm1.
    unsigned short* W1t = (unsigned short*)ws;
    unsigned short* ybuf = (unsigned short*)ws; ws += (size_t)NE * DIMX * HID * 2;
    unsigned short* xb = (unsigned short*)ws; ws += (size_t)T_TOK * DIMX * 2;
    unsigned short* hbuf = (unsigned short*)ws; ws += (size_t)P_PAD * HID * 2;
    int* counts = (int*)ws; ws += 256;
    int* offsets = (int*)ws; ws += 256;
    int* pair_epos = (int*)ws; ws += (size_t)NPAIR * 4;
    float* pair_w = (float*)ws; ws += (size_t)NPAIR * 4;
    int* slot_token = (int*)ws; ws += (size_t)P_PAD * 4;
    float* slot_weight = (float*)ws; ws += (size_t)P_PAD * 4;
    int* tok2slot = (int*)ws; ws += (size_t)NPAIR * 4;

    init_routing_kernel<<<(P_PAD + 255) / 256, 256, 0, stream>>>(slot_token, slot_weight, counts);
    conv_transpose_kernel<<<dim3(HID / 64, DIMX / 64, NE), 256, 0, stream>>>(W1, W1t, DIMX, HID);
    conv_transpose_kernel<<<dim3(DIMX / 64, HID / 64, NE), 256, 0, stream>>>(W2, W2t, HID, DIMX);
    gate_kernel<<<T_TOK / GATE_TPB, 256, 0, stream>>>(x, gw, gb, logits, counts, pair_epos,
                                                      pair_w, xb);
    scan_kernel<<<1, 1, 0, stream>>>(counts, offsets);
    place_kernel<<<NPAIR / 256, 256, 0, stream>>>(pair_epos, pair_w, offsets, slot_token,
                                                  slot_weight, tok2slot);
    // expert on blockIdx.x (gridDim.x=8): flat_id % 8 == expert -> one XCD per expert.
    gemm1_kernel<<<dim3(NE, HID / 128, 128), 256, 0, stream>>>(xb, W1t, b1, offsets, slot_token, hbuf);
    gemm2_kernel<<<dim3(NE, DIMX / 128, 128), 256, 0, stream>>>(hbuf, W2t, b2, offsets, slot_weight, ybuf);
    combine_kernel<<<T_TOK, 256, 0, stream>>>(ybuf, tok2slot, out);
}

// Round 12
// 276.095 us; speedup vs baseline: 1.4525x; 1.0179x over previous
//
#include <hip/hip_runtime.h>
#include <math.h>

#define T_TOK 8192
#define DIMX 1024
#define NE 8
#define HID 2048
#define NPAIR (T_TOK * 2)
#define P_PAD (NPAIR + NE * 128)
#define GATE_TPB 32

typedef __attribute__((ext_vector_type(8))) short s16x8;
typedef __attribute__((ext_vector_type(4))) float f32x4;

static __device__ __forceinline__ unsigned short f2bf(float f) {
    union { float f; unsigned u; } v; v.f = f;
    unsigned r = v.u + 0x7FFFu + ((v.u >> 16) & 1u);
    return (unsigned short)(r >> 16);
}
static __device__ __forceinline__ float bf2f(unsigned short u) {
    union { unsigned u; float f; } v; v.u = (unsigned)u << 16; return v.f;
}

// gelu tanh approximation: v * sigmoid(1.5957691 * v * (1 + 0.044715 v^2))
static __device__ __forceinline__ float gelu_fast(float v) {
    float u2 = -1.5957691216057308f * v * (1.f + 0.044715f * v * v);
    return v * __builtin_amdgcn_rcpf(1.f + __expf(u2));
}

// async global->LDS, 16 bytes per lane. LDS dest must be wave-uniform base + lane*16.
static __device__ __forceinline__ void gload16(const unsigned short* g, unsigned short* l) {
    __builtin_amdgcn_global_load_lds(
        (const __attribute__((address_space(1))) unsigned int*)g,
        (__attribute__((address_space(3))) unsigned int*)l, 16, 0, 0);
}

// ---------------- init: routing slots + counts ----------------
__global__ void init_routing_kernel(int* slot_token, float* slot_weight, int* counts) {
    int i = blockIdx.x * blockDim.x + threadIdx.x;
    if (i < P_PAD) { slot_token[i] = 0; slot_weight[i] = 0.f; }
    if (i < NE) counts[i] = 0;
}

// src [E][R][C] fp32 -> dst [E][C][R] bf16, 64x64 tiles, vectorized both sides
__global__ __launch_bounds__(256) void conv_transpose_kernel(
    const float* __restrict__ src, unsigned short* __restrict__ dst, int R, int C) {
    __shared__ float tile[64][65];
    int e = blockIdx.z;
    int r0 = blockIdx.y * 64, c0 = blockIdx.x * 64;
    const float* s = src + (size_t)e * R * C;
    unsigned short* d = dst + (size_t)e * R * C;
    int tid = threadIdx.x;
    int lr = tid >> 4, lc4 = (tid & 15) * 4;  // 16 rows per pass x 16 float4
    #pragma unroll
    for (int it = 0; it < 4; it++) {
        float4 v = *(const float4*)&s[(size_t)(r0 + it * 16 + lr) * C + c0 + lc4];
        tile[it * 16 + lr][lc4 + 0] = v.x;
        tile[it * 16 + lr][lc4 + 1] = v.y;
        tile[it * 16 + lr][lc4 + 2] = v.z;
        tile[it * 16 + lr][lc4 + 3] = v.w;
    }
    __syncthreads();
    int cc = tid >> 3, rch = (tid & 7) * 8;  // 32 dst rows per pass x 8 chunks of 8
    #pragma unroll
    for (int it = 0; it < 2; it++) {
        int c = it * 32 + cc;
        unsigned short r[8];
        #pragma unroll
        for (int j = 0; j < 8; j++) r[j] = f2bf(tile[rch + j][c]);
        *(uint4*)&d[(size_t)(c0 + c) * R + r0 + rch] = *(const uint4*)&r[0];
    }
}

// ---------------- gating: block-aggregated atomics; also emits xb (bf16 x) ----------------
__global__ __launch_bounds__(256) void gate_kernel(
    const float* __restrict__ x, const float* __restrict__ gw, const float* __restrict__ gb,
    float* __restrict__ logits_out, int* counts, int* __restrict__ pair_epos,
    float* __restrict__ pair_w, unsigned short* __restrict__ xb) {
    __shared__ float sgw[NE * DIMX];
    __shared__ int lcount[NE], lbase[NE];
    __shared__ int s_e[GATE_TPB * 2];
    __shared__ int s_lp[GATE_TPB * 2];
    __shared__ float s_wv[GATE_TPB * 2];
    int tid = threadIdx.x;
    for (int i = tid; i < NE * DIMX / 4; i += 256)
        ((float4*)sgw)[i] = ((const float4*)gw)[i];
    if (tid < NE) lcount[tid] = 0;
    __syncthreads();

    int wave = tid >> 6, lane = tid & 63;
    int tbase = blockIdx.x * GATE_TPB;
    for (int r = 0; r < GATE_TPB / 4; ++r) {
        int ti = wave * (GATE_TPB / 4) + r;
        int t = tbase + ti;
        const float* xr = x + (size_t)t * DIMX;
        float acc[NE] = {};
        #pragma unroll
        for (int i = 0; i < DIMX / 256; i++) {
            float4 xv = *(const float4*)&xr[i * 256 + lane * 4];
            // fold convx: emit bf16 copy of x while it's in registers
            unsigned short rb[4] = { f2bf(xv.x), f2bf(xv.y), f2bf(xv.z), f2bf(xv.w) };
            *(uint2*)&xb[(size_t)t * DIMX + i * 256 + lane * 4] = *(const uint2*)&rb[0];
            #pragma unroll
            for (int e = 0; e < NE; e++) {
                float4 wv = *(const float4*)&sgw[e * DIMX + i * 256 + lane * 4];
                acc[e] += xv.x * wv.x + xv.y * wv.y + xv.z * wv.z + xv.w * wv.w;
            }
        }
        #pragma unroll
        for (int e = 0; e < NE; e++) {
            #pragma unroll
            for (int off = 32; off; off >>= 1) acc[e] += __shfl_xor(acc[e], off);
        }
        if (lane == 0) {
            float* lo = logits_out + (size_t)t * NE;
            #pragma unroll
            for (int e = 0; e < NE; e++) { acc[e] += gb[e]; lo[e] = acc[e]; }
            // top-2 (strict > keeps lowest index on ties, matching jax.lax.top_k)
            float l0 = acc[0]; int e0 = 0;
            #pragma unroll
            for (int e = 1; e < NE; e++) if (acc[e] > l0) { l0 = acc[e]; e0 = e; }
            float l1 = -1e30f; int e1 = -1;
            #pragma unroll
            for (int e = 0; e < NE; e++) if (e != e0 && acc[e] > l1) { l1 = acc[e]; e1 = e; }
            float q = expf(l1 - l0);
            float wn0 = 1.f / (1.f + q);
            float wn1 = q / (1.f + q);
            int lp0 = atomicAdd(&lcount[e0], 1);
            int lp1 = atomicAdd(&lcount[e1], 1);
            s_e[ti * 2] = e0; s_lp[ti * 2] = lp0; s_wv[ti * 2] = wn0;
            s_e[ti * 2 + 1] = e1; s_lp[ti * 2 + 1] = lp1; s_wv[ti * 2 + 1] = wn1;
        }
    }
    __syncthreads();
    if (tid < NE) lbase[tid] = atomicAdd(&counts[tid], lcount[tid]);
    __syncthreads();
    if (tid < GATE_TPB * 2) {
        int e = s_e[tid];
        int gp = lbase[e] + s_lp[tid];
        int gi = (tbase + (tid >> 1)) * 2 + (tid & 1);
        pair_epos[gi] = (e << 28) | gp;
        pair_w[gi] = s_wv[tid];
    }
}

__global__ void scan_kernel(const int* counts, int* offsets) {
    if (threadIdx.x == 0 && blockIdx.x == 0) {
        int o = 0;
        offsets[0] = 0;
        for (int e = 0; e < NE; e++) { o += (counts[e] + 127) & ~127; offsets[e + 1] = o; }
    }
}

__global__ void place_kernel(const int* __restrict__ pair_epos, const float* __restrict__ pair_w,
                             const int* __restrict__ offsets, int* __restrict__ slot_token,
                             float* __restrict__ slot_weight, int* __restrict__ tok2slot) {
    int p = blockIdx.x * 256 + threadIdx.x;
    if (p >= NPAIR) return;
    int ep = pair_epos[p];
    int e = ep >> 28;
    int pos = ep & 0x0FFFFFFF;
    int slot = offsets[e] + pos;
    slot_token[slot] = p >> 1;
    slot_weight[slot] = pair_w[p];
    tok2slot[p] = slot;
}

// pipeline: 2-buffer LDS, depth-1 prefetch, counted vmcnt, raw barriers.
#define BARRIER() asm volatile("s_barrier" ::: "memory")
#define WAIT_VM(n) asm volatile("s_waitcnt vmcnt(" #n ")" ::: "memory")
#define WAIT_LGKM0() do { asm volatile("s_waitcnt lgkmcnt(0)" ::: "memory"); \
                          __builtin_amdgcn_sched_barrier(0); } while (0)

// Swizzled LDS tile layout (both operands), 512 chunks of 16B per 128x32 tile:
//   slot c holds global chunk (row = c>>2, kseg = (c&3) ^ ((c>>3)&3)).
// Write: coalesced (4 lanes per row cover one contiguous permuted 64B segment).
// Read: fragment kseg=lg at lane-constant kx = lg^((lr>>1)&3) -> conflict-free.
// 8 waves/block (512 thr): per-wave output 64x32 -> acc = 8 f32x4 = 32 AGPR;
// arch+acc regs fit 128 -> 4 waves/SIMD (16 waves/CU), 2x the 4-wave version.

// ---------------- grouped GEMM 1: h = gelu(x @ W1 + b1) ----------------
// grid (8=expert, Nn, Nm): expert on blockIdx.x pins expert e -> XCD e (flat%8).
__global__ __launch_bounds__(512, 4) void gemm1_kernel(
    const unsigned short* __restrict__ xb, const unsigned short* __restrict__ W1t,
    const float* __restrict__ b1, const int* __restrict__ offsets,
    const int* __restrict__ slot_token, unsigned short* __restrict__ hbuf) {
    int e = blockIdx.x;
    int row_base = offsets[e];
    int rows = offsets[e + 1] - row_base;
    int m0 = blockIdx.z * 128;
    if (m0 >= rows) return;
    int n0 = blockIdx.y * 128;

    __shared__ unsigned short sA[2][128 * 32];
    __shared__ unsigned short sB[2][128 * 32];

    int tid = threadIdx.x;
    const unsigned short* w1e = W1t + (size_t)e * HID * DIMX;

    int srow = tid >> 2;                      // 0..127
    int kperm = (tid & 3) ^ ((tid >> 3) & 3);
    int tok = slot_token[row_base + m0 + srow];
    const unsigned short* gA0 = xb + (size_t)tok * DIMX + kperm * 8;
    const unsigned short* gB0 = w1e + (size_t)(n0 + srow) * DIMX + kperm * 8;

#define STG1(b, k0) do { \
        gload16(gA0 + (k0), &sA[b][tid * 8]); \
        gload16(gB0 + (k0), &sB[b][tid * 8]); \
    } while (0)

    f32x4 acc[4][2] = {};
    int wid = tid >> 6; int wr = wid >> 2, wc = wid & 3;   // 2m x 4n waves
    int lane = tid & 63; int lr = lane & 15, lg = lane >> 4;
    int kx8 = (lg ^ ((lr >> 1) & 3)) * 8;

#define CMP1(CUR) do { \
        s16x8 af[4], bfr[2]; \
        _Pragma("unroll") \
        for (int m = 0; m < 4; m++) af[m] = *(const s16x8*)&sA[CUR][(wr * 64 + m * 16 + lr) * 32 + kx8]; \
        _Pragma("unroll") \
        for (int n = 0; n < 2; n++) bfr[n] = *(const s16x8*)&sB[CUR][(wc * 32 + n * 16 + lr) * 32 + kx8]; \
        __builtin_amdgcn_s_setprio(1); \
        _Pragma("unroll") \
        for (int m = 0; m < 4; m++) { \
            _Pragma("unroll") \
            for (int n = 0; n < 2; n++) \
                acc[m][n] = __builtin_amdgcn_mfma_f32_16x16x32_bf16(af[m], bfr[n], acc[m][n], 0, 0, 0); \
        } \
        __builtin_amdgcn_s_setprio(0); \
    } while (0)

    const int NT = DIMX / 32;
    STG1(0, 0);
    int cur = 0;
    for (int t = 0; t < NT - 1; ++t) {
        STG1(cur ^ 1, (t + 1) * 32);
        WAIT_VM(2);       // my 2 loads for tile t done; t+1's stay in flight
        BARRIER();
        CMP1(cur);
        WAIT_LGKM0();
        BARRIER();
        cur ^= 1;
    }
    WAIT_VM(0);
    BARRIER();
    CMP1(cur);
#undef STG1
#undef CMP1

    #pragma unroll
    for (int m = 0; m < 4; m++) {
        #pragma unroll
        for (int n = 0; n < 2; n++) {
            int col = n0 + wc * 32 + n * 16 + lr;
            float bias = b1[e * HID + col];
            #pragma unroll
            for (int i = 0; i < 4; i++) {
                int row = wr * 64 + m * 16 + lg * 4 + i;
                float v = gelu_fast(acc[m][n][i] + bias);
                hbuf[(size_t)(row_base + m0 + row) * HID + col] = f2bf(v);
            }
        }
    }
}

// ---------------- grouped GEMM 2: ybuf[slot] = w * (h @ W2 + b2), plain stores ----------------
__global__ __launch_bounds__(512, 4) void gemm2_kernel(
    const unsigned short* __restrict__ hbuf, const unsigned short* __restrict__ W2t,
    const float* __restrict__ b2, const int* __restrict__ offsets,
    const float* __restrict__ slot_weight, unsigned short* __restrict__ ybuf) {
    int e = blockIdx.x;
    int row_base = offsets[e];
    int rows = offsets[e + 1] - row_base;
    int m0 = blockIdx.z * 128;
    if (m0 >= rows) return;
    int n0 = blockIdx.y * 128;

    __shared__ unsigned short sA[2][128 * 32];
    __shared__ unsigned short sB[2][128 * 32];
    __shared__ float s_w[128];

    int tid = threadIdx.x;
    if (tid < 128) s_w[tid] = slot_weight[row_base + m0 + tid];

    const unsigned short* ha = hbuf + (size_t)(row_base + m0) * HID;
    const unsigned short* w2e = W2t + (size_t)e * DIMX * HID;

    int srow = tid >> 2;
    int kperm = (tid & 3) ^ ((tid >> 3) & 3);
    const unsigned short* gA0 = ha + (size_t)srow * HID + kperm * 8;
    const unsigned short* gB0 = w2e + (size_t)(n0 + srow) * HID + kperm * 8;

#define STG2(b, k0) do { \
        gload16(gA0 + (k0), &sA[b][tid * 8]); \
        gload16(gB0 + (k0), &sB[b][tid * 8]); \
    } while (0)

    f32x4 acc[4][2] = {};
    int wid = tid >> 6; int wr = wid >> 2, wc = wid & 3;
    int lane = tid & 63; int lr = lane & 15, lg = lane >> 4;
    int kx8 = (lg ^ ((lr >> 1) & 3)) * 8;

#define CMP2(CUR) do { \
        s16x8 af[4], bfr[2]; \
        _Pragma("unroll") \
        for (int m = 0; m < 4; m++) af[m] = *(const s16x8*)&sA[CUR][(wr * 64 + m * 16 + lr) * 32 + kx8]; \
        _Pragma("unroll") \
        for (int n = 0; n < 2; n++) bfr[n] = *(const s16x8*)&sB[CUR][(wc * 32 + n * 16 + lr) * 32 + kx8]; \
        __builtin_amdgcn_s_setprio(1); \
        _Pragma("unroll") \
        for (int m = 0; m < 4; m++) { \
            _Pragma("unroll") \
            for (int n = 0; n < 2; n++) \
                acc[m][n] = __builtin_amdgcn_mfma_f32_16x16x32_bf16(af[m], bfr[n], acc[m][n], 0, 0, 0); \
        } \
        __builtin_amdgcn_s_setprio(0); \
    } while (0)

    const int NT = HID / 32;
    STG2(0, 0);
    int cur = 0;
    for (int t = 0; t < NT - 1; ++t) {
        STG2(cur ^ 1, (t + 1) * 32);
        WAIT_VM(2);
        BARRIER();
        CMP2(cur);
        WAIT_LGKM0();
        BARRIER();
        cur ^= 1;
    }
    WAIT_VM(0);
    BARRIER();
    CMP2(cur);
#undef STG2
#undef CMP2

    #pragma unroll
    for (int m = 0; m < 4; m++) {
        #pragma unroll
        for (int n = 0; n < 2; n++) {
            int col = n0 + wc * 32 + n * 16 + lr;
            float bias = b2[e * DIMX + col];
            #pragma unroll
            for (int i = 0; i < 4; i++) {
                int row = wr * 64 + m * 16 + lg * 4 + i;
                float v = (acc[m][n][i] + bias) * s_w[row];
                ybuf[(size_t)(row_base + m0 + row) * DIMX + col] = f2bf(v);
            }
        }
    }
}

// ---------------- combine: out[t] = ybuf[slotA] + ybuf[slotB] ----------------
__global__ __launch_bounds__(256) void combine_kernel(
    const unsigned short* __restrict__ ybuf, const int* __restrict__ tok2slot,
    float* __restrict__ out) {
    int t = blockIdx.x;
    int d = threadIdx.x * 4;
    int sa = tok2slot[t * 2], sb = tok2slot[t * 2 + 1];
    ushort4 a = *(const ushort4*)&ybuf[(size_t)sa * DIMX + d];
    ushort4 b = *(const ushort4*)&ybuf[(size_t)sb * DIMX + d];
    float4 o;
    o.x = bf2f(a.x) + bf2f(b.x);
    o.y = bf2f(a.y) + bf2f(b.y);
    o.z = bf2f(a.z) + bf2f(b.z);
    o.w = bf2f(a.w) + bf2f(b.w);
    *(float4*)&out[(size_t)t * DIMX + d] = o;
}

extern "C" void kernel_launch(void* const* d_in, const int* in_sizes, int n_in,
                              void* d_out, int out_size, void* d_ws, size_t ws_size,
                              hipStream_t stream) {
    const float* x  = (const float*)d_in[0];
    const float* gw = (const float*)d_in[1];
    const float* gb = (const float*)d_in[2];
    const float* W1 = (const float*)d_in[3];
    const float* b1 = (const float*)d_in[4];
    const float* W2 = (const float*)d_in[5];
    const float* b2 = (const float*)d_in[6];
    float* out = (float*)d_out;
    float* logits = out + (size_t)T_TOK * DIMX;

    char* ws = (char*)d_ws;
    unsigned short* W2t = (unsigned short*)ws; ws += (size_t)NE * DIMX * HID * 2;
    // ybuf (P_PAD x DIMX bf16 = 35.7 MB) overlays [W1t | xb] (48 MB), both dead after gemm1.
    unsigned short* W1t = (unsigned short*)ws;
    unsigned short* ybuf = (unsigned short*)ws; ws += (size_t)NE * DIMX * HID * 2;
    unsigned short* xb = (unsigned short*)ws; ws += (size_t)T_TOK * DIMX * 2;
    unsigned short* hbuf = (unsigned short*)ws; ws += (size_t)P_PAD * HID * 2;
    int* counts = (int*)ws; ws += 256;
    int* offsets = (int*)ws; ws += 256;
    int* pair_epos = (int*)ws; ws += (size_t)NPAIR * 4;
    float* pair_w = (float*)ws; ws += (size_t)NPAIR * 4;
    int* slot_token = (int*)ws; ws += (size_t)P_PAD * 4;
    float* slot_weight = (float*)ws; ws += (size_t)P_PAD * 4;
    int* tok2slot = (int*)ws; ws += (size_t)NPAIR * 4;

    init_routing_kernel<<<(P_PAD + 255) / 256, 256, 0, stream>>>(slot_token, slot_weight, counts);
    conv_transpose_kernel<<<dim3(HID / 64, DIMX / 64, NE), 256, 0, stream>>>(W1, W1t, DIMX, HID);
    conv_transpose_kernel<<<dim3(DIMX / 64, HID / 64, NE), 256, 0, stream>>>(W2, W2t, HID, DIMX);
    gate_kernel<<<T_TOK / GATE_TPB, 256, 0, stream>>>(x, gw, gb, logits, counts, pair_epos,
                                                      pair_w, xb);
    scan_kernel<<<1, 1, 0, stream>>>(counts, offsets);
    place_kernel<<<NPAIR / 256, 256, 0, stream>>>(pair_epos, pair_w, offsets, slot_token,
                                                  slot_weight, tok2slot);
    // expert on blockIdx.x (gridDim.x=8): flat_id % 8 == expert -> one XCD per expert.
    gemm1_kernel<<<dim3(NE, HID / 128, 128), 512, 0, stream>>>(xb, W1t, b1, offsets, slot_token, hbuf);
    gemm2_kernel<<<dim3(NE, DIMX / 128, 128), 512, 0, stream>>>(hbuf, W2t, b2, offsets, slot_weight, ybuf);
    combine_kernel<<<T_TOK, 256, 0, stream>>>(ybuf, tok2slot, out);
}

// Round 13
// 272.528 us; speedup vs baseline: 1.4715x; 1.0131x over previous
//
#include <hip/hip_runtime.h>
#include <math.h>

#define T_TOK 8192
#define DIMX 1024
#define NE 8
#define HID 2048
#define NPAIR (T_TOK * 2)
#define P_PAD (NPAIR + NE * 128)
#define GATE_TPB 32

typedef __attribute__((ext_vector_type(8))) short s16x8;
typedef __attribute__((ext_vector_type(4))) float f32x4;

static __device__ __forceinline__ unsigned short f2bf(float f) {
    union { float f; unsigned u; } v; v.f = f;
    unsigned r = v.u + 0x7FFFu + ((v.u >> 16) & 1u);
    return (unsigned short)(r >> 16);
}
static __device__ __forceinline__ float bf2f(unsigned short u) {
    union { unsigned u; float f; } v; v.u = (unsigned)u << 16; return v.f;
}

// gelu tanh approximation: v * sigmoid(1.5957691 * v * (1 + 0.044715 v^2))
static __device__ __forceinline__ float gelu_fast(float v) {
    float u2 = -1.5957691216057308f * v * (1.f + 0.044715f * v * v);
    return v * __builtin_amdgcn_rcpf(1.f + __expf(u2));
}

// async global->LDS, 16 bytes per lane. LDS dest must be wave-uniform base + lane*16.
static __device__ __forceinline__ void gload16(const unsigned short* g, unsigned short* l) {
    __builtin_amdgcn_global_load_lds(
        (const __attribute__((address_space(1))) unsigned int*)g,
        (__attribute__((address_space(3))) unsigned int*)l, 16, 0, 0);
}

// ---------------- init: routing slots + counts ----------------
__global__ void init_routing_kernel(int* slot_token, float* slot_weight, int* counts) {
    int i = blockIdx.x * blockDim.x + threadIdx.x;
    if (i < P_PAD) { slot_token[i] = 0; slot_weight[i] = 0.f; }
    if (i < NE) counts[i] = 0;
}

// src [E][R][C] fp32 -> dst [E][C][R] bf16, 64x64 tiles, vectorized both sides
__global__ __launch_bounds__(256) void conv_transpose_kernel(
    const float* __restrict__ src, unsigned short* __restrict__ dst, int R, int C) {
    __shared__ float tile[64][65];
    int e = blockIdx.z;
    int r0 = blockIdx.y * 64, c0 = blockIdx.x * 64;
    const float* s = src + (size_t)e * R * C;
    unsigned short* d = dst + (size_t)e * R * C;
    int tid = threadIdx.x;
    int lr = tid >> 4, lc4 = (tid & 15) * 4;  // 16 rows per pass x 16 float4
    #pragma unroll
    for (int it = 0; it < 4; it++) {
        float4 v = *(const float4*)&s[(size_t)(r0 + it * 16 + lr) * C + c0 + lc4];
        tile[it * 16 + lr][lc4 + 0] = v.x;
        tile[it * 16 + lr][lc4 + 1] = v.y;
        tile[it * 16 + lr][lc4 + 2] = v.z;
        tile[it * 16 + lr][lc4 + 3] = v.w;
    }
    __syncthreads();
    int cc = tid >> 3, rch = (tid & 7) * 8;  // 32 dst rows per pass x 8 chunks of 8
    #pragma unroll
    for (int it = 0; it < 2; it++) {
        int c = it * 32 + cc;
        unsigned short r[8];
        #pragma unroll
        for (int j = 0; j < 8; j++) r[j] = f2bf(tile[rch + j][c]);
        *(uint4*)&d[(size_t)(c0 + c) * R + r0 + rch] = *(const uint4*)&r[0];
    }
}

// ---------------- gating: block-aggregated atomics; also emits xb (bf16 x) ----------------
__global__ __launch_bounds__(256) void gate_kernel(
    const float* __restrict__ x, const float* __restrict__ gw, const float* __restrict__ gb,
    float* __restrict__ logits_out, int* counts, int* __restrict__ pair_epos,
    float* __restrict__ pair_w, unsigned short* __restrict__ xb) {
    __shared__ float sgw[NE * DIMX];
    __shared__ int lcount[NE], lbase[NE];
    __shared__ int s_e[GATE_TPB * 2];
    __shared__ int s_lp[GATE_TPB * 2];
    __shared__ float s_wv[GATE_TPB * 2];
    int tid = threadIdx.x;
    for (int i = tid; i < NE * DIMX / 4; i += 256)
        ((float4*)sgw)[i] = ((const float4*)gw)[i];
    if (tid < NE) lcount[tid] = 0;
    __syncthreads();

    int wave = tid >> 6, lane = tid & 63;
    int tbase = blockIdx.x * GATE_TPB;
    for (int r = 0; r < GATE_TPB / 4; ++r) {
        int ti = wave * (GATE_TPB / 4) + r;
        int t = tbase + ti;
        const float* xr = x + (size_t)t * DIMX;
        float acc[NE] = {};
        #pragma unroll
        for (int i = 0; i < DIMX / 256; i++) {
            float4 xv = *(const float4*)&xr[i * 256 + lane * 4];
            // fold convx: emit bf16 copy of x while it's in registers
            unsigned short rb[4] = { f2bf(xv.x), f2bf(xv.y), f2bf(xv.z), f2bf(xv.w) };
            *(uint2*)&xb[(size_t)t * DIMX + i * 256 + lane * 4] = *(const uint2*)&rb[0];
            #pragma unroll
            for (int e = 0; e < NE; e++) {
                float4 wv = *(const float4*)&sgw[e * DIMX + i * 256 + lane * 4];
                acc[e] += xv.x * wv.x + xv.y * wv.y + xv.z * wv.z + xv.w * wv.w;
            }
        }
        #pragma unroll
        for (int e = 0; e < NE; e++) {
            #pragma unroll
            for (int off = 32; off; off >>= 1) acc[e] += __shfl_xor(acc[e], off);
        }
        if (lane == 0) {
            float* lo = logits_out + (size_t)t * NE;
            #pragma unroll
            for (int e = 0; e < NE; e++) { acc[e] += gb[e]; lo[e] = acc[e]; }
            // top-2 (strict > keeps lowest index on ties, matching jax.lax.top_k)
            float l0 = acc[0]; int e0 = 0;
            #pragma unroll
            for (int e = 1; e < NE; e++) if (acc[e] > l0) { l0 = acc[e]; e0 = e; }
            float l1 = -1e30f; int e1 = -1;
            #pragma unroll
            for (int e = 0; e < NE; e++) if (e != e0 && acc[e] > l1) { l1 = acc[e]; e1 = e; }
            float q = expf(l1 - l0);
            float wn0 = 1.f / (1.f + q);
            float wn1 = q / (1.f + q);
            int lp0 = atomicAdd(&lcount[e0], 1);
            int lp1 = atomicAdd(&lcount[e1], 1);
            s_e[ti * 2] = e0; s_lp[ti * 2] = lp0; s_wv[ti * 2] = wn0;
            s_e[ti * 2 + 1] = e1; s_lp[ti * 2 + 1] = lp1; s_wv[ti * 2 + 1] = wn1;
        }
    }
    __syncthreads();
    if (tid < NE) lbase[tid] = atomicAdd(&counts[tid], lcount[tid]);
    __syncthreads();
    if (tid < GATE_TPB * 2) {
        int e = s_e[tid];
        int gp = lbase[e] + s_lp[tid];
        int gi = (tbase + (tid >> 1)) * 2 + (tid & 1);
        pair_epos[gi] = (e << 28) | gp;
        pair_w[gi] = s_wv[tid];
    }
}

__global__ void scan_kernel(const int* counts, int* offsets) {
    if (threadIdx.x == 0 && blockIdx.x == 0) {
        int o = 0;
        offsets[0] = 0;
        for (int e = 0; e < NE; e++) { o += (counts[e] + 127) & ~127; offsets[e + 1] = o; }
    }
}

__global__ void place_kernel(const int* __restrict__ pair_epos, const float* __restrict__ pair_w,
                             const int* __restrict__ offsets, int* __restrict__ slot_token,
                             float* __restrict__ slot_weight, int* __restrict__ tok2slot) {
    int p = blockIdx.x * 256 + threadIdx.x;
    if (p >= NPAIR) return;
    int ep = pair_epos[p];
    int e = ep >> 28;
    int pos = ep & 0x0FFFFFFF;
    int slot = offsets[e] + pos;
    slot_token[slot] = p >> 1;
    slot_weight[slot] = pair_w[p];
    tok2slot[p] = slot;
}

// pipeline: 2-buffer LDS, BK=64, depth-1 prefetch, counted vmcnt, raw barriers.
#define BARRIER() asm volatile("s_barrier" ::: "memory")
#define WAIT_VM(n) asm volatile("s_waitcnt vmcnt(" #n ")" ::: "memory")
#define WAIT_LGKM0() do { asm volatile("s_waitcnt lgkmcnt(0)" ::: "memory"); \
                          __builtin_amdgcn_sched_barrier(0); } while (0)

// Swizzled LDS tile layout, 1024 chunks of 16B per 128x64 tile:
//   slot c holds global chunk (row = c>>3, kseg = (c&7) ^ (row&7)).
// Write: 8 threads per row cover the row's contiguous 128B (permuted) -> coalesced.
// Read: fragment (row, kseg = kk*4+lg) at slot row*8 + (kseg ^ (row&7));
//   kx = (kk*4+lg) ^ (lr&7): any aligned 8-lane window hits all 8 bank-groups once.
// BK=64: 16 MFMA per phase per wave, 2x issue-to-use distance, half the barriers.

// ---------------- grouped GEMM 1: h = gelu(x @ W1 + b1) ----------------
// grid (8=expert, Nn, Nm): expert on blockIdx.x pins expert e -> XCD e (flat%8).
__global__ __launch_bounds__(512, 4) void gemm1_kernel(
    const unsigned short* __restrict__ xb, const unsigned short* __restrict__ W1t,
    const float* __restrict__ b1, const int* __restrict__ offsets,
    const int* __restrict__ slot_token, unsigned short* __restrict__ hbuf) {
    int e = blockIdx.x;
    int row_base = offsets[e];
    int rows = offsets[e + 1] - row_base;
    int m0 = blockIdx.z * 128;
    if (m0 >= rows) return;
    int n0 = blockIdx.y * 128;

    __shared__ unsigned short sA[2][128 * 64];
    __shared__ unsigned short sB[2][128 * 64];

    int tid = threadIdx.x;
    const unsigned short* w1e = W1t + (size_t)e * HID * DIMX;

    int srow = tid >> 3;                       // 0..63
    int kperm = (tid & 7) ^ (srow & 7);
    int tok0 = slot_token[row_base + m0 + srow];
    int tok1 = slot_token[row_base + m0 + srow + 64];
    const unsigned short* gA0 = xb + (size_t)tok0 * DIMX + kperm * 8;
    const unsigned short* gA1 = xb + (size_t)tok1 * DIMX + kperm * 8;
    const unsigned short* gB0 = w1e + (size_t)(n0 + srow) * DIMX + kperm * 8;
    const unsigned short* gB1 = w1e + (size_t)(n0 + srow + 64) * DIMX + kperm * 8;

#define STG1(b, k0) do { \
        gload16(gA0 + (k0), &sA[b][tid * 8]); \
        gload16(gA1 + (k0), &sA[b][(tid + 512) * 8]); \
        gload16(gB0 + (k0), &sB[b][tid * 8]); \
        gload16(gB1 + (k0), &sB[b][(tid + 512) * 8]); \
    } while (0)

    f32x4 acc[4][2] = {};
    int wid = tid >> 6; int wr = wid >> 2, wc = wid & 3;   // 2m x 4n waves
    int lane = tid & 63; int lr = lane & 15, lg = lane >> 4;
    int kx0 = lg ^ (lr & 7);                   // k-subtile 0; subtile 1 = kx0^4

#define CMP1(CUR) do { \
        _Pragma("unroll") \
        for (int kk = 0; kk < 2; kk++) { \
            int kxo = (kx0 ^ (kk * 4)) * 8; \
            s16x8 af[4], bfr[2]; \
            _Pragma("unroll") \
            for (int m = 0; m < 4; m++) af[m] = *(const s16x8*)&sA[CUR][(wr * 64 + m * 16 + lr) * 64 + kxo]; \
            _Pragma("unroll") \
            for (int n = 0; n < 2; n++) bfr[n] = *(const s16x8*)&sB[CUR][(wc * 32 + n * 16 + lr) * 64 + kxo]; \
            __builtin_amdgcn_s_setprio(1); \
            _Pragma("unroll") \
            for (int m = 0; m < 4; m++) { \
                _Pragma("unroll") \
                for (int n = 0; n < 2; n++) \
                    acc[m][n] = __builtin_amdgcn_mfma_f32_16x16x32_bf16(af[m], bfr[n], acc[m][n], 0, 0, 0); \
            } \
            __builtin_amdgcn_s_setprio(0); \
        } \
    } while (0)

    const int NT = DIMX / 64;
    STG1(0, 0);
    int cur = 0;
    for (int t = 0; t < NT - 1; ++t) {
        STG1(cur ^ 1, (t + 1) * 64);
        WAIT_VM(4);       // my 4 loads for tile t done; t+1's stay in flight
        BARRIER();
        CMP1(cur);
        WAIT_LGKM0();
        BARRIER();
        cur ^= 1;
    }
    WAIT_VM(0);
    BARRIER();
    CMP1(cur);
#undef STG1
#undef CMP1

    #pragma unroll
    for (int m = 0; m < 4; m++) {
        #pragma unroll
        for (int n = 0; n < 2; n++) {
            int col = n0 + wc * 32 + n * 16 + lr;
            float bias = b1[e * HID + col];
            #pragma unroll
            for (int i = 0; i < 4; i++) {
                int row = wr * 64 + m * 16 + lg * 4 + i;
                float v = gelu_fast(acc[m][n][i] + bias);
                hbuf[(size_t)(row_base + m0 + row) * HID + col] = f2bf(v);
            }
        }
    }
}

// ---------------- grouped GEMM 2: ybuf[slot] = w * (h @ W2 + b2), plain stores ----------------
__global__ __launch_bounds__(512, 4) void gemm2_kernel(
    const unsigned short* __restrict__ hbuf, const unsigned short* __restrict__ W2t,
    const float* __restrict__ b2, const int* __restrict__ offsets,
    const float* __restrict__ slot_weight, unsigned short* __restrict__ ybuf) {
    int e = blockIdx.x;
    int row_base = offsets[e];
    int rows = offsets[e + 1] - row_base;
    int m0 = blockIdx.z * 128;
    if (m0 >= rows) return;
    int n0 = blockIdx.y * 128;

    __shared__ unsigned short sA[2][128 * 64];
    __shared__ unsigned short sB[2][128 * 64];
    __shared__ float s_w[128];

    int tid = threadIdx.x;
    if (tid < 128) s_w[tid] = slot_weight[row_base + m0 + tid];

    const unsigned short* ha = hbuf + (size_t)(row_base + m0) * HID;
    const unsigned short* w2e = W2t + (size_t)e * DIMX * HID;

    int srow = tid >> 3;
    int kperm = (tid & 7) ^ (srow & 7);
    const unsigned short* gA0 = ha + (size_t)srow * HID + kperm * 8;
    const unsigned short* gA1 = ha + (size_t)(srow + 64) * HID + kperm * 8;
    const unsigned short* gB0 = w2e + (size_t)(n0 + srow) * HID + kperm * 8;
    const unsigned short* gB1 = w2e + (size_t)(n0 + srow + 64) * HID + kperm * 8;

#define STG2(b, k0) do { \
        gload16(gA0 + (k0), &sA[b][tid * 8]); \
        gload16(gA1 + (k0), &sA[b][(tid + 512) * 8]); \
        gload16(gB0 + (k0), &sB[b][tid * 8]); \
        gload16(gB1 + (k0), &sB[b][(tid + 512) * 8]); \
    } while (0)

    f32x4 acc[4][2] = {};
    int wid = tid >> 6; int wr = wid >> 2, wc = wid & 3;
    int lane = tid & 63; int lr = lane & 15, lg = lane >> 4;
    int kx0 = lg ^ (lr & 7);

#define CMP2(CUR) do { \
        _Pragma("unroll") \
        for (int kk = 0; kk < 2; kk++) { \
            int kxo = (kx0 ^ (kk * 4)) * 8; \
            s16x8 af[4], bfr[2]; \
            _Pragma("unroll") \
            for (int m = 0; m < 4; m++) af[m] = *(const s16x8*)&sA[CUR][(wr * 64 + m * 16 + lr) * 64 + kxo]; \
            _Pragma("unroll") \
            for (int n = 0; n < 2; n++) bfr[n] = *(const s16x8*)&sB[CUR][(wc * 32 + n * 16 + lr) * 64 + kxo]; \
            __builtin_amdgcn_s_setprio(1); \
            _Pragma("unroll") \
            for (int m = 0; m < 4; m++) { \
                _Pragma("unroll") \
                for (int n = 0; n < 2; n++) \
                    acc[m][n] = __builtin_amdgcn_mfma_f32_16x16x32_bf16(af[m], bfr[n], acc[m][n], 0, 0, 0); \
            } \
            __builtin_amdgcn_s_setprio(0); \
        } \
    } while (0)

    const int NT = HID / 64;
    STG2(0, 0);
    int cur = 0;
    for (int t = 0; t < NT - 1; ++t) {
        STG2(cur ^ 1, (t + 1) * 64);
        WAIT_VM(4);
        BARRIER();
        CMP2(cur);
        WAIT_LGKM0();
        BARRIER();
        cur ^= 1;
    }
    WAIT_VM(0);
    BARRIER();
    CMP2(cur);
#undef STG2
#undef CMP2

    #pragma unroll
    for (int m = 0; m < 4; m++) {
        #pragma unroll
        for (int n = 0; n < 2; n++) {
            int col = n0 + wc * 32 + n * 16 + lr;
            float bias = b2[e * DIMX + col];
            #pragma unroll
            for (int i = 0; i < 4; i++) {
                int row = wr * 64 + m * 16 + lg * 4 + i;
                float v = (acc[m][n][i] + bias) * s_w[row];
                ybuf[(size_t)(row_base + m0 + row) * DIMX + col] = f2bf(v);
            }
        }
    }
}

// ---------------- combine: out[t] = ybuf[slotA] + ybuf[slotB] ----------------
__global__ __launch_bounds__(256) void combine_kernel(
    const unsigned short* __restrict__ ybuf, const int* __restrict__ tok2slot,
    float* __restrict__ out) {
    int t = blockIdx.x;
    int d = threadIdx.x * 4;
    int sa = tok2slot[t * 2], sb = tok2slot[t * 2 + 1];
    ushort4 a = *(const ushort4*)&ybuf[(size_t)sa * DIMX + d];
    ushort4 b = *(const ushort4*)&ybuf[(size_t)sb * DIMX + d];
    float4 o;
    o.x = bf2f(a.x) + bf2f(b.x);
    o.y = bf2f(a.y) + bf2f(b.y);
    o.z = bf2f(a.z) + bf2f(b.z);
    o.w = bf2f(a.w) + bf2f(b.w);
    *(float4*)&out[(size_t)t * DIMX + d] = o;
}

extern "C" void kernel_launch(void* const* d_in, const int* in_sizes, int n_in,
                              void* d_out, int out_size, void* d_ws, size_t ws_size,
                              hipStream_t stream) {
    const float* x  = (const float*)d_in[0];
    const float* gw = (const float*)d_in[1];
    const float* gb = (const float*)d_in[2];
    const float* W1 = (const float*)d_in[3];
    const float* b1 = (const float*)d_in[4];
    const float* W2 = (const float*)d_in[5];
    const float* b2 = (const float*)d_in[6];
    float* out = (float*)d_out;
    float* logits = out + (size_t)T_TOK * DIMX;

    char* ws = (char*)d_ws;
    unsigned short* W2t = (unsigned short*)ws; ws += (size_t)NE * DIMX * HID * 2;
    // ybuf (P_PAD x DIMX bf16 = 35.7 MB) overlays [W1t | xb] (48 MB), both dead after gemm1.
    unsigned short* W1t = (unsigned short*)ws;
    unsigned short* ybuf = (unsigned short*)ws; ws += (size_t)NE * DIMX * HID * 2;
    unsigned short* xb = (unsigned short*)ws; ws += (size_t)T_TOK * DIMX * 2;
    unsigned short* hbuf = (unsigned short*)ws; ws += (size_t)P_PAD * HID * 2;
    int* counts = (int*)ws; ws += 256;
    int* offsets = (int*)ws; ws += 256;
    int* pair_epos = (int*)ws; ws += (size_t)NPAIR * 4;
    float* pair_w = (float*)ws; ws += (size_t)NPAIR * 4;
    int* slot_token = (int*)ws; ws += (size_t)P_PAD * 4;
    float* slot_weight = (float*)ws; ws += (size_t)P_PAD * 4;
    int* tok2slot = (int*)ws; ws += (size_t)NPAIR * 4;

    init_routing_kernel<<<(P_PAD + 255) / 256, 256, 0, stream>>>(slot_token, slot_weight, counts);
    conv_transpose_kernel<<<dim3(HID / 64, DIMX / 64, NE), 256, 0, stream>>>(W1, W1t, DIMX, HID);
    conv_transpose_kernel<<<dim3(DIMX / 64, HID / 64, NE), 256, 0, stream>>>(W2, W2t, HID, DIMX);
    gate_kernel<<<T_TOK / GATE_TPB, 256, 0, stream>>>(x, gw, gb, logits, counts, pair_epos,
                                                      pair_w, xb);
    scan_kernel<<<1, 1, 0, stream>>>(counts, offsets);
    place_kernel<<<NPAIR / 256, 256, 0, stream>>>(pair_epos, pair_w, offsets, slot_token,
                                                  slot_weight, tok2slot);
    // expert on blockIdx.x (gridDim.x=8): flat_id % 8 == expert -> one XCD per expert.
    gemm1_kernel<<<dim3(NE, HID / 128, 128), 512, 0, stream>>>(xb, W1t, b1, offsets, slot_token, hbuf);
    gemm2_kernel<<<dim3(NE, DIMX / 128, 128), 512, 0, stream>>>(hbuf, W2t, b2, offsets, slot_weight, ybuf);
    combine_kernel<<<T_TOK, 256, 0, stream>>>(ybuf, tok2slot, out);
}